// Round 11
// baseline (326.110 us; speedup 1.0000x reference)
//
#include <hip/hip_runtime.h>

#define N_NODES 50000
#define N_HEDGES 5000
#define NNZ 800000
#define IN_C 128
#define D1 256
#define D2 64
#define SN 64    // fixed stride: hedges per node row (deg mean 16, 12 sigma safe)
#define SH 256   // fixed stride: nodes per hedge row (deg mean 160, 7.6 sigma safe)

typedef unsigned int u32;
typedef unsigned short u16;
typedef __attribute__((ext_vector_type(8))) short short8;
typedef __attribute__((ext_vector_type(4))) float f32x4;

// ---- bf16 helpers: storage bf16, math f32 ----
__device__ __forceinline__ float bf_lo(u32 u) { return __uint_as_float(u << 16); }
__device__ __forceinline__ float bf_hi(u32 u) { return __uint_as_float(u & 0xffff0000u); }
__device__ __forceinline__ u32 rne16(float f) {
    u32 u = __float_as_uint(f);
    return (u + 0x7fffu + ((u >> 16) & 1u)) >> 16;
}
__device__ __forceinline__ u32 pack2(float a, float b) {
    return rne16(a) | (rne16(b) << 16);
}
__device__ __forceinline__ void acc8(float* a, uint4 v) {
    a[0] += bf_lo(v.x); a[1] += bf_hi(v.x);
    a[2] += bf_lo(v.y); a[3] += bf_hi(v.y);
    a[4] += bf_lo(v.z); a[5] += bf_hi(v.z);
    a[6] += bf_lo(v.w); a[7] += bf_hi(v.w);
}

// ---------------- fused: cast x->bf16 + fill adjacency + pack W2 ----------------
__global__ void cast_fill(const float4* __restrict__ x, uint2* __restrict__ xb,
                          const int* __restrict__ nidx, const int* __restrict__ hidx,
                          int* __restrict__ cur_n, int* __restrict__ cur_h,
                          u16* __restrict__ adj_n, u16* __restrict__ adj_h,
                          const float* __restrict__ W2, u16* __restrict__ w2hi,
                          u16* __restrict__ w2lo) {
    int i = blockIdx.x * 256 + threadIdx.x;
    float4 v = x[i];
    uint2 o;
    o.x = pack2(v.x, v.y);
    o.y = pack2(v.z, v.w);
    xb[i] = o;
    if (i < NNZ / 2) {
        int e0 = i * 2;
        int n0 = nidx[e0],     h0 = hidx[e0];
        int n1 = nidx[e0 + 1], h1 = hidx[e0 + 1];
        int p0 = atomicAdd(&cur_n[n0], 1);
        int p1 = atomicAdd(&cur_n[n1], 1);
        int q0 = atomicAdd(&cur_h[h0], 1);
        int q1 = atomicAdd(&cur_h[h1], 1);
        adj_n[n0 * SN + (p0 & (SN - 1))] = (u16)h0;
        adj_n[n1 * SN + (p1 & (SN - 1))] = (u16)h1;
        adj_h[h0 * SH + (q0 & (SH - 1))] = (u16)n0;
        adj_h[h1 * SH + (q1 & (SH - 1))] = (u16)n1;
    }
    if (i < 16384) {
        int kc = i >> 11;
        int nt = (i >> 9) & 3;
        int l = (i >> 3) & 63;
        int j = i & 7;
        int k = kc * 32 + (l >> 4) * 8 + j;
        int n = nt * 16 + (l & 15);
        float w = W2[k * D2 + n];
        u32 h = rne16(w);
        float res = w - bf_lo(h);
        w2hi[i] = (u16)h;
        w2lo[i] = (u16)rne16(res);
    }
}

// ---------------- bf16-source pull-gather, 16-deep prefetch, fused 1/len (+bias+relu) ----------------
template <int F, int S, bool BIAS_RELU, bool DST_BF16>
__global__ void gatherb(const uint4* __restrict__ src, const int* __restrict__ cur,
                        const u16* __restrict__ adj, const float4* __restrict__ bias,
                        void* __restrict__ dst, int nrows) {
    constexpr int L = F / 8;
    int gid = blockIdx.x * 256 + threadIdx.x;
    int row = gid / L;
    if (row >= nrows) return;
    int c = gid - row * L;
    int len = cur[row];
    int lenc = (len < S) ? len : S;
    int s = row * S, e = s + lenc;
    float a0[8] = {0,0,0,0,0,0,0,0}, a1[8] = {0,0,0,0,0,0,0,0};
    int j = s;
    for (; j + 15 < e; j += 16) {
        uint4 aa = *(const uint4*)(adj + j);
        uint4 ab = *(const uint4*)(adj + j + 8);
        int i0 = aa.x & 0xffff, i1 = aa.x >> 16;
        int i2 = aa.y & 0xffff, i3 = aa.y >> 16;
        int i4 = aa.z & 0xffff, i5 = aa.z >> 16;
        int i6 = aa.w & 0xffff, i7 = aa.w >> 16;
        int k0 = ab.x & 0xffff, k1 = ab.x >> 16;
        int k2 = ab.y & 0xffff, k3 = ab.y >> 16;
        int k4 = ab.z & 0xffff, k5 = ab.z >> 16;
        int k6 = ab.w & 0xffff, k7 = ab.w >> 16;
        uint4 v0 = src[i0 * L + c];
        uint4 v1 = src[i1 * L + c];
        uint4 v2 = src[i2 * L + c];
        uint4 v3 = src[i3 * L + c];
        uint4 v4 = src[i4 * L + c];
        uint4 v5 = src[i5 * L + c];
        uint4 v6 = src[i6 * L + c];
        uint4 v7 = src[i7 * L + c];
        uint4 w0 = src[k0 * L + c];
        uint4 w1 = src[k1 * L + c];
        uint4 w2 = src[k2 * L + c];
        uint4 w3 = src[k3 * L + c];
        uint4 w4 = src[k4 * L + c];
        uint4 w5 = src[k5 * L + c];
        uint4 w6 = src[k6 * L + c];
        uint4 w7 = src[k7 * L + c];
        acc8(a0, v0); acc8(a1, v1); acc8(a0, v2); acc8(a1, v3);
        acc8(a0, v4); acc8(a1, v5); acc8(a0, v6); acc8(a1, v7);
        acc8(a0, w0); acc8(a1, w1); acc8(a0, w2); acc8(a1, w3);
        acc8(a0, w4); acc8(a1, w5); acc8(a0, w6); acc8(a1, w7);
    }
    for (; j + 7 < e; j += 8) {
        uint4 aa = *(const uint4*)(adj + j);
        int i0 = aa.x & 0xffff, i1 = aa.x >> 16;
        int i2 = aa.y & 0xffff, i3 = aa.y >> 16;
        int i4 = aa.z & 0xffff, i5 = aa.z >> 16;
        int i6 = aa.w & 0xffff, i7 = aa.w >> 16;
        uint4 v0 = src[i0 * L + c];
        uint4 v1 = src[i1 * L + c];
        uint4 v2 = src[i2 * L + c];
        uint4 v3 = src[i3 * L + c];
        uint4 v4 = src[i4 * L + c];
        uint4 v5 = src[i5 * L + c];
        uint4 v6 = src[i6 * L + c];
        uint4 v7 = src[i7 * L + c];
        acc8(a0, v0); acc8(a1, v1); acc8(a0, v2); acc8(a1, v3);
        acc8(a0, v4); acc8(a1, v5); acc8(a0, v6); acc8(a1, v7);
    }
    for (; j < e; j++) {
        uint4 v = src[(int)adj[j] * L + c];
        acc8(a0, v);
    }
    float inv = (len > 0) ? 1.f / (float)len : 0.f;
    float r[8];
#pragma unroll
    for (int t = 0; t < 8; t++) r[t] = (a0[t] + a1[t]) * inv;
    if (BIAS_RELU) {
        float4 b0 = bias[c * 2], b1v = bias[c * 2 + 1];
        r[0] = fmaxf(r[0] + b0.x, 0.f); r[1] = fmaxf(r[1] + b0.y, 0.f);
        r[2] = fmaxf(r[2] + b0.z, 0.f); r[3] = fmaxf(r[3] + b0.w, 0.f);
        r[4] = fmaxf(r[4] + b1v.x, 0.f); r[5] = fmaxf(r[5] + b1v.y, 0.f);
        r[6] = fmaxf(r[6] + b1v.z, 0.f); r[7] = fmaxf(r[7] + b1v.w, 0.f);
    }
    if (DST_BF16) {
        uint4 o;
        o.x = pack2(r[0], r[1]);
        o.y = pack2(r[2], r[3]);
        o.z = pack2(r[4], r[5]);
        o.w = pack2(r[6], r[7]);
        ((uint4*)dst)[row * L + c] = o;
    } else {
        float4* d = (float4*)dst;
        d[row * (F / 4) + c * 2]     = make_float4(r[0], r[1], r[2], r[3]);
        d[row * (F / 4) + c * 2 + 1] = make_float4(r[4], r[5], r[6], r[7]);
    }
}

// ---------------- e1 = aggx @ W1  [5000,128]@[128,256], bf16 out ----------------
__global__ void gemm1(const float* __restrict__ aggx, const float* __restrict__ W1,
                      u16* __restrict__ e1b) {
    __shared__ float a[4][IN_C];
    int h0 = blockIdx.x * 4;
    int tid = threadIdx.x;  // 256
    if (tid < 128) {
        float4 v = ((const float4*)aggx)[h0 * 32 + tid];
        int r = tid >> 5, k4 = (tid & 31) * 4;
        a[r][k4] = v.x; a[r][k4 + 1] = v.y; a[r][k4 + 2] = v.z; a[r][k4 + 3] = v.w;
    }
    __syncthreads();
    float acc0 = 0.f, acc1 = 0.f, acc2 = 0.f, acc3 = 0.f;
    for (int k = 0; k < IN_C; k++) {
        float w = W1[k * D1 + tid];
        acc0 += a[0][k] * w;
        acc1 += a[1][k] * w;
        acc2 += a[2][k] * w;
        acc3 += a[3][k] * w;
    }
    e1b[(h0 + 0) * D1 + tid] = (u16)rne16(acc0);
    e1b[(h0 + 1) * D1 + tid] = (u16)rne16(acc1);
    e1b[(h0 + 2) * D1 + tid] = (u16)rne16(acc2);
    e1b[(h0 + 3) * D1 + tid] = (u16)rne16(acc3);
}

// ---------------- hw = hb @ W2 via MFMA (double-bf16 W2), 32 nodes/block ----------------
__global__ void hw_mfma(const u16* __restrict__ hb, const short8* __restrict__ w2hi,
                        const short8* __restrict__ w2lo, u16* __restrict__ hw) {
    int tid = threadIdx.x;
    int wave = tid >> 6;
    int lane = tid & 63;
    int node0 = blockIdx.x * 32;
    int m = lane & 15;
    int q = lane >> 4;
    const u16* arow0 = hb + (node0 + m) * D1 + q * 8;
    const u16* arow1 = hb + (node0 + 16 + m) * D1 + q * 8;
    f32x4 acc0 = {0.f, 0.f, 0.f, 0.f};
    f32x4 acc1 = {0.f, 0.f, 0.f, 0.f};
#pragma unroll
    for (int kc = 0; kc < 8; kc++) {
        short8 a0 = *(const short8*)(arow0 + kc * 32);
        short8 a1 = *(const short8*)(arow1 + kc * 32);
        short8 bh = w2hi[(kc * 4 + wave) * 64 + lane];
        short8 bl = w2lo[(kc * 4 + wave) * 64 + lane];
        acc0 = __builtin_amdgcn_mfma_f32_16x16x32_bf16(a0, bh, acc0, 0, 0, 0);
        acc0 = __builtin_amdgcn_mfma_f32_16x16x32_bf16(a0, bl, acc0, 0, 0, 0);
        acc1 = __builtin_amdgcn_mfma_f32_16x16x32_bf16(a1, bh, acc1, 0, 0, 0);
        acc1 = __builtin_amdgcn_mfma_f32_16x16x32_bf16(a1, bl, acc1, 0, 0, 0);
    }
    int col = lane & 15;
    int r0 = q * 4;
#pragma unroll
    for (int r = 0; r < 4; r++) {
        hw[(node0 + r0 + r) * D2 + wave * 16 + col] = (u16)rne16(acc0[r]);
        hw[(node0 + 16 + r0 + r) * D2 + wave * 16 + col] = (u16)rne16(acc1[r]);
    }
}

extern "C" void kernel_launch(void* const* d_in, const int* in_sizes, int n_in,
                              void* d_out, int out_size, void* d_ws, size_t ws_size,
                              hipStream_t stream) {
    const float* x  = (const float*)d_in[0];
    const int* edge = (const int*)d_in[1];
    const int* nidx = edge;         // edge[0, :]
    const int* hidx = edge + NNZ;   // edge[1, :]
    const float* W1 = (const float*)d_in[2];
    const float* b1 = (const float*)d_in[3];
    const float* W2 = (const float*)d_in[4];
    const float* b2 = (const float*)d_in[5];
    float* out = (float*)d_out;

    // ---- workspace layout (all chunks 16B-aligned) ----
    float* aggx = (float*)d_ws;               // 5000*128 f32  = 640,000
    u16* e2b    = (u16*)(aggx + N_HEDGES * IN_C); // 5000*64 u16 = 320,000
    u16* xb     = e2b + N_HEDGES * D2;        // 50000*128 u16 = 6,400,000
    u16* e1b    = xb + N_NODES * IN_C;        // 5000*256  u16 = 1,280,000
    u16* hb     = e1b + N_HEDGES * D1;        // 50000*256 u16 = 12,800,000
    u16* hwb    = hb + N_NODES * D1;          // 50000*64  u16 = 3,200,000
    u16* w2hi   = hwb + N_NODES * D2;         // 16384 u16
    u16* w2lo   = w2hi + 16384;               // 16384 u16
    u16* adj_n  = w2lo + 16384;               // 50000*64 u16 = 3,200,000
    u16* adj_h  = adj_n + N_NODES * SN;       // 5000*256 u16 = 1,280,000
    int* cur_n  = (int*)(adj_h + N_HEDGES * SH); // 50000 (zeroed)
    int* cur_h  = cur_n + N_NODES;               // 5000  (zeroed)
    size_t zero_ints = N_NODES + N_HEDGES;       // 220 KB
    // total ≈ 57 MB

    hipMemsetAsync(cur_n, 0, zero_ints * sizeof(int), stream);

    // fused: cast + fill adjacency + pack W2
    cast_fill<<<N_NODES * IN_C / 4 / 256, 256, 0, stream>>>(
        (const float4*)x, (uint2*)xb, nidx, hidx, cur_n, cur_h,
        adj_n, adj_h, W2, w2hi, w2lo);

    // layer 1: aggx = Binv * gather(xb);  e1b = aggx @ W1 (bf16)
    gatherb<IN_C, SH, false, false><<<(N_HEDGES * (IN_C / 8) + 255) / 256, 256, 0, stream>>>(
        (const uint4*)xb, cur_h, adj_h, nullptr, aggx, N_HEDGES);
    gemm1<<<N_HEDGES / 4, 256, 0, stream>>>(aggx, W1, e1b);
    // h = relu(Dinv*gather(e1b)+b1) -> hb (bf16)
    gatherb<D1, SN, true, true><<<N_NODES * (D1 / 8) / 256, 256, 0, stream>>>(
        (const uint4*)e1b, cur_n, adj_n, (const float4*)b1, hb, N_NODES);

    // hw = hb @ W2 (MFMA, double-bf16 W2, 32 nodes/block)
    hw_mfma<<<N_NODES / 32, 256, 0, stream>>>(hb, (const short8*)w2hi,
                                              (const short8*)w2lo, hwb);

    // layer 2: e2b = Binv * gather(hwb) (bf16); out = relu(Dinv*gather(e2b)+b2) (f32)
    gatherb<D2, SH, false, true><<<(N_HEDGES * (D2 / 8) + 255) / 256, 256, 0, stream>>>(
        (const uint4*)hwb, cur_h, adj_h, nullptr, e2b, N_HEDGES);
    gatherb<D2, SN, true, false><<<(N_NODES * (D2 / 8) + 255) / 256, 256, 0, stream>>>(
        (const uint4*)e2b, cur_n, adj_n, (const float4*)b2, out, N_NODES);
}

// Round 12
// 306.036 us; speedup vs baseline: 1.0656x; 1.0656x over previous
//
#include <hip/hip_runtime.h>

#define N_NODES 50000
#define N_HEDGES 5000
#define NNZ 800000
#define IN_C 128
#define D1 256
#define D2 64
#define SN 64    // fixed stride: hedges per node row (deg mean 16, 12 sigma safe)
#define SH 256   // fixed stride: nodes per hedge row (deg mean 160, 7.6 sigma safe)

typedef unsigned int u32;
typedef unsigned short u16;
typedef __attribute__((ext_vector_type(8))) short short8;
typedef __attribute__((ext_vector_type(4))) float f32x4;

// ---- bf16 helpers: storage bf16, math f32 ----
__device__ __forceinline__ float bf_lo(u32 u) { return __uint_as_float(u << 16); }
__device__ __forceinline__ float bf_hi(u32 u) { return __uint_as_float(u & 0xffff0000u); }
__device__ __forceinline__ u32 rne16(float f) {
    u32 u = __float_as_uint(f);
    return (u + 0x7fffu + ((u >> 16) & 1u)) >> 16;
}
__device__ __forceinline__ u32 pack2(float a, float b) {
    return rne16(a) | (rne16(b) << 16);
}
__device__ __forceinline__ void acc8(float* a, uint4 v) {
    a[0] += bf_lo(v.x); a[1] += bf_hi(v.x);
    a[2] += bf_lo(v.y); a[3] += bf_hi(v.y);
    a[4] += bf_lo(v.z); a[5] += bf_hi(v.z);
    a[6] += bf_lo(v.w); a[7] += bf_hi(v.w);
}

// ---------------- fused: cast x->bf16 + fill adjacency + pack W2 ----------------
__global__ void cast_fill(const float4* __restrict__ x, uint2* __restrict__ xb,
                          const int* __restrict__ nidx, const int* __restrict__ hidx,
                          int* __restrict__ cur_n, int* __restrict__ cur_h,
                          u16* __restrict__ adj_n, u16* __restrict__ adj_h,
                          const float* __restrict__ W2, u16* __restrict__ w2hi,
                          u16* __restrict__ w2lo) {
    int i = blockIdx.x * 256 + threadIdx.x;
    float4 v = x[i];
    uint2 o;
    o.x = pack2(v.x, v.y);
    o.y = pack2(v.z, v.w);
    xb[i] = o;
    if (i < NNZ / 2) {
        int e0 = i * 2;
        int n0 = nidx[e0],     h0 = hidx[e0];
        int n1 = nidx[e0 + 1], h1 = hidx[e0 + 1];
        int p0 = atomicAdd(&cur_n[n0], 1);
        int p1 = atomicAdd(&cur_n[n1], 1);
        int q0 = atomicAdd(&cur_h[h0], 1);
        int q1 = atomicAdd(&cur_h[h1], 1);
        adj_n[n0 * SN + (p0 & (SN - 1))] = (u16)h0;
        adj_n[n1 * SN + (p1 & (SN - 1))] = (u16)h1;
        adj_h[h0 * SH + (q0 & (SH - 1))] = (u16)n0;
        adj_h[h1 * SH + (q1 & (SH - 1))] = (u16)n1;
    }
    if (i < 16384) {
        int kc = i >> 11;
        int nt = (i >> 9) & 3;
        int l = (i >> 3) & 63;
        int j = i & 7;
        int k = kc * 32 + (l >> 4) * 8 + j;
        int n = nt * 16 + (l & 15);
        float w = W2[k * D2 + n];
        u32 h = rne16(w);
        float res = w - bf_lo(h);
        w2hi[i] = (u16)h;
        w2lo[i] = (u16)rne16(res);
    }
}

// ---------------- bf16-source pull-gather, vec-adj, prefetch-8, 4 acc banks ----------------
template <int F, int S, bool BIAS_RELU, bool DST_BF16>
__global__ void gatherb(const uint4* __restrict__ src, const int* __restrict__ cur,
                        const u16* __restrict__ adj, const float4* __restrict__ bias,
                        void* __restrict__ dst, int nrows) {
    constexpr int L = F / 8;
    int gid = blockIdx.x * 256 + threadIdx.x;
    int row = gid / L;
    if (row >= nrows) return;
    int c = gid - row * L;
    int len = cur[row];
    int lenc = (len < S) ? len : S;
    int s = row * S, e = s + lenc;
    float a0[8] = {0,0,0,0,0,0,0,0}, a1[8] = {0,0,0,0,0,0,0,0};
    float a2[8] = {0,0,0,0,0,0,0,0}, a3[8] = {0,0,0,0,0,0,0,0};
    int j = s;
    for (; j + 7 < e; j += 8) {
        uint4 aa = *(const uint4*)(adj + j);   // 8 indices in one 16B load
        int i0 = aa.x & 0xffff, i1 = aa.x >> 16;
        int i2 = aa.y & 0xffff, i3 = aa.y >> 16;
        int i4 = aa.z & 0xffff, i5 = aa.z >> 16;
        int i6 = aa.w & 0xffff, i7 = aa.w >> 16;
        uint4 v0 = src[i0 * L + c];
        uint4 v1 = src[i1 * L + c];
        uint4 v2 = src[i2 * L + c];
        uint4 v3 = src[i3 * L + c];
        uint4 v4 = src[i4 * L + c];
        uint4 v5 = src[i5 * L + c];
        uint4 v6 = src[i6 * L + c];
        uint4 v7 = src[i7 * L + c];
        acc8(a0, v0); acc8(a1, v1); acc8(a2, v2); acc8(a3, v3);
        acc8(a0, v4); acc8(a1, v5); acc8(a2, v6); acc8(a3, v7);
    }
    for (; j < e; j++) {
        uint4 v = src[(int)adj[j] * L + c];
        acc8(a0, v);
    }
    float inv = (len > 0) ? 1.f / (float)len : 0.f;
    float r[8];
#pragma unroll
    for (int t = 0; t < 8; t++) r[t] = ((a0[t] + a1[t]) + (a2[t] + a3[t])) * inv;
    if (BIAS_RELU) {
        float4 b0 = bias[c * 2], b1v = bias[c * 2 + 1];
        r[0] = fmaxf(r[0] + b0.x, 0.f); r[1] = fmaxf(r[1] + b0.y, 0.f);
        r[2] = fmaxf(r[2] + b0.z, 0.f); r[3] = fmaxf(r[3] + b0.w, 0.f);
        r[4] = fmaxf(r[4] + b1v.x, 0.f); r[5] = fmaxf(r[5] + b1v.y, 0.f);
        r[6] = fmaxf(r[6] + b1v.z, 0.f); r[7] = fmaxf(r[7] + b1v.w, 0.f);
    }
    if (DST_BF16) {
        uint4 o;
        o.x = pack2(r[0], r[1]);
        o.y = pack2(r[2], r[3]);
        o.z = pack2(r[4], r[5]);
        o.w = pack2(r[6], r[7]);
        ((uint4*)dst)[row * L + c] = o;
    } else {
        float4* d = (float4*)dst;
        d[row * (F / 4) + c * 2]     = make_float4(r[0], r[1], r[2], r[3]);
        d[row * (F / 4) + c * 2 + 1] = make_float4(r[4], r[5], r[6], r[7]);
    }
}

// ---------------- e1 = aggx @ W1  [5000,128]@[128,256], bf16 out ----------------
__global__ void gemm1(const float* __restrict__ aggx, const float* __restrict__ W1,
                      u16* __restrict__ e1b) {
    __shared__ float a[4][IN_C];
    int h0 = blockIdx.x * 4;
    int tid = threadIdx.x;  // 256
    if (tid < 128) {
        float4 v = ((const float4*)aggx)[h0 * 32 + tid];
        int r = tid >> 5, k4 = (tid & 31) * 4;
        a[r][k4] = v.x; a[r][k4 + 1] = v.y; a[r][k4 + 2] = v.z; a[r][k4 + 3] = v.w;
    }
    __syncthreads();
    float acc0 = 0.f, acc1 = 0.f, acc2 = 0.f, acc3 = 0.f;
    for (int k = 0; k < IN_C; k++) {
        float w = W1[k * D1 + tid];
        acc0 += a[0][k] * w;
        acc1 += a[1][k] * w;
        acc2 += a[2][k] * w;
        acc3 += a[3][k] * w;
    }
    e1b[(h0 + 0) * D1 + tid] = (u16)rne16(acc0);
    e1b[(h0 + 1) * D1 + tid] = (u16)rne16(acc1);
    e1b[(h0 + 2) * D1 + tid] = (u16)rne16(acc2);
    e1b[(h0 + 3) * D1 + tid] = (u16)rne16(acc3);
}

// ---------------- hw = hb @ W2 via MFMA (double-bf16 W2), 32 nodes/block ----------------
__global__ void hw_mfma(const u16* __restrict__ hb, const short8* __restrict__ w2hi,
                        const short8* __restrict__ w2lo, u16* __restrict__ hw) {
    int tid = threadIdx.x;
    int wave = tid >> 6;
    int lane = tid & 63;
    int node0 = blockIdx.x * 32;
    int m = lane & 15;
    int q = lane >> 4;
    const u16* arow0 = hb + (node0 + m) * D1 + q * 8;
    const u16* arow1 = hb + (node0 + 16 + m) * D1 + q * 8;
    f32x4 acc0 = {0.f, 0.f, 0.f, 0.f};
    f32x4 acc1 = {0.f, 0.f, 0.f, 0.f};
#pragma unroll
    for (int kc = 0; kc < 8; kc++) {
        short8 a0 = *(const short8*)(arow0 + kc * 32);
        short8 a1 = *(const short8*)(arow1 + kc * 32);
        short8 bh = w2hi[(kc * 4 + wave) * 64 + lane];
        short8 bl = w2lo[(kc * 4 + wave) * 64 + lane];
        acc0 = __builtin_amdgcn_mfma_f32_16x16x32_bf16(a0, bh, acc0, 0, 0, 0);
        acc0 = __builtin_amdgcn_mfma_f32_16x16x32_bf16(a0, bl, acc0, 0, 0, 0);
        acc1 = __builtin_amdgcn_mfma_f32_16x16x32_bf16(a1, bh, acc1, 0, 0, 0);
        acc1 = __builtin_amdgcn_mfma_f32_16x16x32_bf16(a1, bl, acc1, 0, 0, 0);
    }
    int col = lane & 15;
    int r0 = q * 4;
#pragma unroll
    for (int r = 0; r < 4; r++) {
        hw[(node0 + r0 + r) * D2 + wave * 16 + col] = (u16)rne16(acc0[r]);
        hw[(node0 + 16 + r0 + r) * D2 + wave * 16 + col] = (u16)rne16(acc1[r]);
    }
}

extern "C" void kernel_launch(void* const* d_in, const int* in_sizes, int n_in,
                              void* d_out, int out_size, void* d_ws, size_t ws_size,
                              hipStream_t stream) {
    const float* x  = (const float*)d_in[0];
    const int* edge = (const int*)d_in[1];
    const int* nidx = edge;         // edge[0, :]
    const int* hidx = edge + NNZ;   // edge[1, :]
    const float* W1 = (const float*)d_in[2];
    const float* b1 = (const float*)d_in[3];
    const float* W2 = (const float*)d_in[4];
    const float* b2 = (const float*)d_in[5];
    float* out = (float*)d_out;

    // ---- workspace layout (all chunks 16B-aligned) ----
    float* aggx = (float*)d_ws;               // 5000*128 f32  = 640,000
    u16* e2b    = (u16*)(aggx + N_HEDGES * IN_C); // 5000*64 u16 = 320,000
    u16* xb     = e2b + N_HEDGES * D2;        // 50000*128 u16 = 6,400,000
    u16* e1b    = xb + N_NODES * IN_C;        // 5000*256  u16 = 1,280,000
    u16* hb     = e1b + N_HEDGES * D1;        // 50000*256 u16 = 12,800,000
    u16* hwb    = hb + N_NODES * D1;          // 50000*64  u16 = 3,200,000
    u16* w2hi   = hwb + N_NODES * D2;         // 16384 u16
    u16* w2lo   = w2hi + 16384;               // 16384 u16
    u16* adj_n  = w2lo + 16384;               // 50000*64 u16 = 3,200,000
    u16* adj_h  = adj_n + N_NODES * SN;       // 5000*256 u16 = 1,280,000
    int* cur_n  = (int*)(adj_h + N_HEDGES * SH); // 50000 (zeroed)
    int* cur_h  = cur_n + N_NODES;               // 5000  (zeroed)
    size_t zero_ints = N_NODES + N_HEDGES;       // 220 KB
    // total ≈ 57 MB

    hipMemsetAsync(cur_n, 0, zero_ints * sizeof(int), stream);

    // fused: cast + fill adjacency + pack W2
    cast_fill<<<N_NODES * IN_C / 4 / 256, 256, 0, stream>>>(
        (const float4*)x, (uint2*)xb, nidx, hidx, cur_n, cur_h,
        adj_n, adj_h, W2, w2hi, w2lo);

    // layer 1: aggx = Binv * gather(xb);  e1b = aggx @ W1 (bf16)
    gatherb<IN_C, SH, false, false><<<(N_HEDGES * (IN_C / 8) + 255) / 256, 256, 0, stream>>>(
        (const uint4*)xb, cur_h, adj_h, nullptr, aggx, N_HEDGES);
    gemm1<<<N_HEDGES / 4, 256, 0, stream>>>(aggx, W1, e1b);
    // h = relu(Dinv*gather(e1b)+b1) -> hb (bf16)
    gatherb<D1, SN, true, true><<<N_NODES * (D1 / 8) / 256, 256, 0, stream>>>(
        (const uint4*)e1b, cur_n, adj_n, (const float4*)b1, hb, N_NODES);

    // hw = hb @ W2 (MFMA, double-bf16 W2, 32 nodes/block)
    hw_mfma<<<N_NODES / 32, 256, 0, stream>>>(hb, (const short8*)w2hi,
                                              (const short8*)w2lo, hwb);

    // layer 2: e2b = Binv * gather(hwb) (bf16); out = relu(Dinv*gather(e2b)+b2) (f32)
    gatherb<D2, SH, false, true><<<(N_HEDGES * (D2 / 8) + 255) / 256, 256, 0, stream>>>(
        (const uint4*)hwb, cur_h, adj_h, nullptr, e2b, N_HEDGES);
    gatherb<D2, SN, true, false><<<(N_NODES * (D2 / 8) + 255) / 256, 256, 0, stream>>>(
        (const uint4*)e2b, cur_n, adj_n, (const float4*)b2, out, N_NODES);
}

// Round 13
// 288.584 us; speedup vs baseline: 1.1300x; 1.0605x over previous
//
#include <hip/hip_runtime.h>

#define N_NODES 50000
#define N_HEDGES 5000
#define NNZ 800000
#define IN_C 128
#define D1 256
#define D2 64
#define SN 64    // fixed stride: hedges per node row (deg mean 16, 12 sigma safe)
#define SH 256   // fixed stride: nodes per hedge row (deg mean 160, 7.6 sigma safe)

typedef unsigned int u32;
typedef unsigned short u16;
typedef __attribute__((ext_vector_type(8))) short short8;
typedef __attribute__((ext_vector_type(4))) float f32x4;

// ---- bf16 helpers: storage bf16, math f32 ----
__device__ __forceinline__ float bf_lo(u32 u) { return __uint_as_float(u << 16); }
__device__ __forceinline__ float bf_hi(u32 u) { return __uint_as_float(u & 0xffff0000u); }
__device__ __forceinline__ u32 rne16(float f) {
    u32 u = __float_as_uint(f);
    return (u + 0x7fffu + ((u >> 16) & 1u)) >> 16;
}
__device__ __forceinline__ u32 pack2(float a, float b) {
    return rne16(a) | (rne16(b) << 16);
}
__device__ __forceinline__ void acc8(float* a, uint4 v) {
    a[0] += bf_lo(v.x); a[1] += bf_hi(v.x);
    a[2] += bf_lo(v.y); a[3] += bf_hi(v.y);
    a[4] += bf_lo(v.z); a[5] += bf_hi(v.z);
    a[6] += bf_lo(v.w); a[7] += bf_hi(v.w);
}

// ---------------- fused: cast x->bf16 + fill adjacency + pack W1/W2 ----------------
// MFMA B-frag layout (16x16x32): lane l holds B[k=(l>>4)*8+j][n=l&15], j=0..7.
__global__ void cast_fill(const float4* __restrict__ x, uint2* __restrict__ xb,
                          const int* __restrict__ nidx, const int* __restrict__ hidx,
                          int* __restrict__ cur_n, int* __restrict__ cur_h,
                          u16* __restrict__ adj_n, u16* __restrict__ adj_h,
                          const float* __restrict__ W1, u16* __restrict__ w1hi,
                          u16* __restrict__ w1lo,
                          const float* __restrict__ W2, u16* __restrict__ w2hi,
                          u16* __restrict__ w2lo) {
    int i = blockIdx.x * 256 + threadIdx.x;
    float4 v = x[i];
    uint2 o;
    o.x = pack2(v.x, v.y);
    o.y = pack2(v.z, v.w);
    xb[i] = o;
    if (i < NNZ / 2) {
        int e0 = i * 2;
        int n0 = nidx[e0],     h0 = hidx[e0];
        int n1 = nidx[e0 + 1], h1 = hidx[e0 + 1];
        int p0 = atomicAdd(&cur_n[n0], 1);
        int p1 = atomicAdd(&cur_n[n1], 1);
        int q0 = atomicAdd(&cur_h[h0], 1);
        int q1 = atomicAdd(&cur_h[h1], 1);
        adj_n[n0 * SN + (p0 & (SN - 1))] = (u16)h0;
        adj_n[n1 * SN + (p1 & (SN - 1))] = (u16)h1;
        adj_h[h0 * SH + (q0 & (SH - 1))] = (u16)n0;
        adj_h[h1 * SH + (q1 & (SH - 1))] = (u16)n1;
    }
    if (i < 32768) {  // W1: kc=0..3 (K=128), ct=0..15 (N=256)
        int j = i & 7;
        int l = (i >> 3) & 63;
        int ct = (i >> 9) & 15;
        int kc = i >> 13;
        int k = kc * 32 + (l >> 4) * 8 + j;
        int n = ct * 16 + (l & 15);
        float w = W1[k * D1 + n];
        u32 h = rne16(w);
        w1hi[i] = (u16)h;
        w1lo[i] = (u16)rne16(w - bf_lo(h));
    } else if (i < 32768 + 16384) {  // W2: kc=0..7 (K=256), nt=0..3 (N=64)
        int t = i - 32768;
        int j = t & 7;
        int l = (t >> 3) & 63;
        int nt = (t >> 9) & 3;
        int kc = t >> 11;
        int k = kc * 32 + (l >> 4) * 8 + j;
        int n = nt * 16 + (l & 15);
        float w = W2[k * D2 + n];
        u32 h = rne16(w);
        w2hi[t] = (u16)h;
        w2lo[t] = (u16)rne16(w - bf_lo(h));
    }
}

// ---------------- bf16-source pull-gather, vec-adj, prefetch-8, 4 acc banks ----------------
template <int F, int S, bool BIAS_RELU, bool DST_BF16>
__global__ void gatherb(const uint4* __restrict__ src, const int* __restrict__ cur,
                        const u16* __restrict__ adj, const float4* __restrict__ bias,
                        void* __restrict__ dst, int nrows) {
    constexpr int L = F / 8;
    int gid = blockIdx.x * 256 + threadIdx.x;
    int row = gid / L;
    if (row >= nrows) return;
    int c = gid - row * L;
    int len = cur[row];
    int lenc = (len < S) ? len : S;
    int s = row * S, e = s + lenc;
    float a0[8] = {0,0,0,0,0,0,0,0}, a1[8] = {0,0,0,0,0,0,0,0};
    float a2[8] = {0,0,0,0,0,0,0,0}, a3[8] = {0,0,0,0,0,0,0,0};
    int j = s;
    for (; j + 7 < e; j += 8) {
        uint4 aa = *(const uint4*)(adj + j);   // 8 indices in one 16B load
        int i0 = aa.x & 0xffff, i1 = aa.x >> 16;
        int i2 = aa.y & 0xffff, i3 = aa.y >> 16;
        int i4 = aa.z & 0xffff, i5 = aa.z >> 16;
        int i6 = aa.w & 0xffff, i7 = aa.w >> 16;
        uint4 v0 = src[i0 * L + c];
        uint4 v1 = src[i1 * L + c];
        uint4 v2 = src[i2 * L + c];
        uint4 v3 = src[i3 * L + c];
        uint4 v4 = src[i4 * L + c];
        uint4 v5 = src[i5 * L + c];
        uint4 v6 = src[i6 * L + c];
        uint4 v7 = src[i7 * L + c];
        acc8(a0, v0); acc8(a1, v1); acc8(a2, v2); acc8(a3, v3);
        acc8(a0, v4); acc8(a1, v5); acc8(a2, v6); acc8(a3, v7);
    }
    for (; j < e; j++) {
        uint4 v = src[(int)adj[j] * L + c];
        acc8(a0, v);
    }
    float inv = (len > 0) ? 1.f / (float)len : 0.f;
    float r[8];
#pragma unroll
    for (int t = 0; t < 8; t++) r[t] = ((a0[t] + a1[t]) + (a2[t] + a3[t])) * inv;
    if (BIAS_RELU) {
        float4 b0 = bias[c * 2], b1v = bias[c * 2 + 1];
        r[0] = fmaxf(r[0] + b0.x, 0.f); r[1] = fmaxf(r[1] + b0.y, 0.f);
        r[2] = fmaxf(r[2] + b0.z, 0.f); r[3] = fmaxf(r[3] + b0.w, 0.f);
        r[4] = fmaxf(r[4] + b1v.x, 0.f); r[5] = fmaxf(r[5] + b1v.y, 0.f);
        r[6] = fmaxf(r[6] + b1v.z, 0.f); r[7] = fmaxf(r[7] + b1v.w, 0.f);
    }
    if (DST_BF16) {
        uint4 o;
        o.x = pack2(r[0], r[1]);
        o.y = pack2(r[2], r[3]);
        o.z = pack2(r[4], r[5]);
        o.w = pack2(r[6], r[7]);
        ((uint4*)dst)[row * L + c] = o;
    } else {
        float4* d = (float4*)dst;
        d[row * (F / 4) + c * 2]     = make_float4(r[0], r[1], r[2], r[3]);
        d[row * (F / 4) + c * 2 + 1] = make_float4(r[4], r[5], r[6], r[7]);
    }
}

// ---------------- fused node MLP: hw = relu(sb @ W1 + b1) @ W2  (MFMA) ----------------
// 16 nodes/block, 256 threads = 4 waves. sb rows are Dinv-scaled gathers (bf16).
// Phase 1: each wave computes 4 col-tiles of h (16 cols each) via double-bf16 W1.
// h (bf16) staged in LDS (stride 264 u16 = 528 B: 16B-aligned, 2-way banks = free).
// Phase 2: each wave computes 16 cols of hw via double-bf16 W2, A from LDS.
#define HSTRIDE 264
__global__ void node_mlp(const uint4* __restrict__ sb4,
                         const short8* __restrict__ w1hi, const short8* __restrict__ w1lo,
                         const float* __restrict__ b1,
                         const short8* __restrict__ w2hi, const short8* __restrict__ w2lo,
                         u16* __restrict__ hw) {
    __shared__ u16 hs[16 * HSTRIDE];  // 8448 B
    int tid = threadIdx.x;
    int wave = tid >> 6;
    int lane = tid & 63;
    int node0 = blockIdx.x * 16;
    int m = lane & 15;
    int q = lane >> 4;
    // A-fragments: lane holds sb[node0+m][kc*32 + q*8 .. +8]
    short8 a[4];
    const uint4* srow = sb4 + (node0 + m) * 16 + q;
#pragma unroll
    for (int kc = 0; kc < 4; kc++) {
        uint4 t = srow[kc * 4];
        a[kc] = *(short8*)&t;
    }
#pragma unroll
    for (int i = 0; i < 4; i++) {
        int ct = wave * 4 + i;
        f32x4 acc = {0.f, 0.f, 0.f, 0.f};
#pragma unroll
        for (int kc = 0; kc < 4; kc++) {
            acc = __builtin_amdgcn_mfma_f32_16x16x32_bf16(a[kc], w1hi[(kc * 16 + ct) * 64 + lane], acc, 0, 0, 0);
            acc = __builtin_amdgcn_mfma_f32_16x16x32_bf16(a[kc], w1lo[(kc * 16 + ct) * 64 + lane], acc, 0, 0, 0);
        }
        int col = ct * 16 + m;   // C layout: col = lane&15
        float bc = b1[col];
#pragma unroll
        for (int r = 0; r < 4; r++) {
            float h = fmaxf(acc[r] + bc, 0.f);   // row = q*4 + r
            hs[(q * 4 + r) * HSTRIDE + col] = (u16)rne16(h);
        }
    }
    __syncthreads();
    // Phase 2: A from LDS: lane reads h[m][kc*32 + q*8 .. +8]
    f32x4 acc = {0.f, 0.f, 0.f, 0.f};
#pragma unroll
    for (int kc = 0; kc < 8; kc++) {
        short8 ah = *(const short8*)&hs[m * HSTRIDE + kc * 32 + q * 8];
        acc = __builtin_amdgcn_mfma_f32_16x16x32_bf16(ah, w2hi[(kc * 4 + wave) * 64 + lane], acc, 0, 0, 0);
        acc = __builtin_amdgcn_mfma_f32_16x16x32_bf16(ah, w2lo[(kc * 4 + wave) * 64 + lane], acc, 0, 0, 0);
    }
#pragma unroll
    for (int r = 0; r < 4; r++) {
        hw[(node0 + q * 4 + r) * D2 + wave * 16 + m] = (u16)rne16(acc[r]);
    }
}

extern "C" void kernel_launch(void* const* d_in, const int* in_sizes, int n_in,
                              void* d_out, int out_size, void* d_ws, size_t ws_size,
                              hipStream_t stream) {
    const float* x  = (const float*)d_in[0];
    const int* edge = (const int*)d_in[1];
    const int* nidx = edge;         // edge[0, :]
    const int* hidx = edge + NNZ;   // edge[1, :]
    const float* W1 = (const float*)d_in[2];
    const float* b1 = (const float*)d_in[3];
    const float* W2 = (const float*)d_in[4];
    const float* b2 = (const float*)d_in[5];
    float* out = (float*)d_out;

    // ---- workspace layout (all chunks 16B-aligned) ----
    u16* xb     = (u16*)d_ws;                 // 50000*128 u16 = 6,400,000
    u16* aggxb  = xb + N_NODES * IN_C;        // 5000*128  u16 = 640,000
    u16* sb     = aggxb + N_HEDGES * IN_C;    // 50000*128 u16 = 6,400,000
    u16* hwb    = sb + N_NODES * IN_C;        // 50000*64  u16 = 3,200,000
    u16* e2b    = hwb + N_NODES * D2;         // 5000*64   u16 = 320,000
    u16* w1hi   = e2b + N_HEDGES * D2;        // 32768 u16
    u16* w1lo   = w1hi + 32768;               // 32768 u16
    u16* w2hi   = w1lo + 32768;               // 16384 u16
    u16* w2lo   = w2hi + 16384;               // 16384 u16
    u16* adj_n  = w2lo + 16384;               // 50000*64 u16 = 3,200,000
    u16* adj_h  = adj_n + N_NODES * SN;       // 5000*256 u16 = 1,280,000
    int* cur_n  = (int*)(adj_h + N_HEDGES * SH); // 50000 (zeroed)
    int* cur_h  = cur_n + N_NODES;               // 5000  (zeroed)
    size_t zero_ints = N_NODES + N_HEDGES;       // 220 KB
    // total ≈ 43 MB

    hipMemsetAsync(cur_n, 0, zero_ints * sizeof(int), stream);

    // fused: cast + fill adjacency + pack W1/W2 double-bf16 fragments
    cast_fill<<<N_NODES * IN_C / 4 / 256, 256, 0, stream>>>(
        (const float4*)x, (uint2*)xb, nidx, hidx, cur_n, cur_h,
        adj_n, adj_h, W1, w1hi, w1lo, W2, w2hi, w2lo);

    // aggxb = Binv * gather_h(xb)   [5000 x 128 bf16]
    gatherb<IN_C, SH, false, true><<<(N_HEDGES * (IN_C / 8) + 255) / 256, 256, 0, stream>>>(
        (const uint4*)xb, cur_h, adj_h, nullptr, aggxb, N_HEDGES);
    // sb = Dinv * gather_n(aggxb)   [50000 x 128 bf16]   (W1 commuted to the right)
    gatherb<IN_C, SN, false, true><<<(N_NODES * (IN_C / 8) + 255) / 256, 256, 0, stream>>>(
        (const uint4*)aggxb, cur_n, adj_n, nullptr, sb, N_NODES);

    // hw = relu(sb @ W1 + b1) @ W2   [50000 x 64 bf16]  (fused MFMA)
    node_mlp<<<N_NODES / 16, 256, 0, stream>>>(
        (const uint4*)sb, (const short8*)w1hi, (const short8*)w1lo, b1,
        (const short8*)w2hi, (const short8*)w2lo, hwb);

    // layer 2: e2b = Binv * gather_h(hwb); out = relu(Dinv * gather_n(e2b) + b2)
    gatherb<D2, SH, false, true><<<(N_HEDGES * (D2 / 8) + 255) / 256, 256, 0, stream>>>(
        (const uint4*)hwb, cur_h, adj_h, nullptr, e2b, N_HEDGES);
    gatherb<D2, SN, true, false><<<(N_NODES * (D2 / 8) + 255) / 256, 256, 0, stream>>>(
        (const uint4*)e2b, cur_n, adj_n, (const float4*)b2, out, N_NODES);
}

// Round 14
// 248.365 us; speedup vs baseline: 1.3130x; 1.1619x over previous
//
#include <hip/hip_runtime.h>

#define N_NODES 50000
#define N_HEDGES 5000
#define NNZ 800000
#define IN_C 128
#define D1 256
#define D2 64
#define SN 64    // fixed stride: hedges per node row (deg mean 16, 12 sigma safe)
#define SH 256   // fixed stride: nodes per hedge row (deg mean 160, 7.6 sigma safe)

// bucketed adjacency build
#define HBK 20     // hedges per bucket
#define NHB 250    // hedge buckets
#define HCAP 4096  // pair capacity per hedge bucket (mean 3200, 16 sigma)
#define NBK 100    // nodes per bucket
#define NNB 500    // node buckets
#define NCAP 2048  // pair capacity per node bucket (mean 1600, 11 sigma)

typedef unsigned int u32;
typedef unsigned short u16;
typedef __attribute__((ext_vector_type(8))) short short8;
typedef __attribute__((ext_vector_type(4))) float f32x4;

// ---- bf16 helpers: storage bf16, math f32 ----
__device__ __forceinline__ float bf_lo(u32 u) { return __uint_as_float(u << 16); }
__device__ __forceinline__ float bf_hi(u32 u) { return __uint_as_float(u & 0xffff0000u); }
__device__ __forceinline__ u32 rne16(float f) {
    u32 u = __float_as_uint(f);
    return (u + 0x7fffu + ((u >> 16) & 1u)) >> 16;
}
__device__ __forceinline__ u32 pack2(float a, float b) {
    return rne16(a) | (rne16(b) << 16);
}
__device__ __forceinline__ void acc8(float* a, uint4 v) {
    a[0] += bf_lo(v.x); a[1] += bf_hi(v.x);
    a[2] += bf_lo(v.y); a[3] += bf_hi(v.y);
    a[4] += bf_lo(v.z); a[5] += bf_hi(v.z);
    a[6] += bf_lo(v.w); a[7] += bf_hi(v.w);
}

// ---------------- cast x->bf16 + pack W1/W2 double-bf16 MFMA fragments ----------------
__global__ void cast_pack(const float4* __restrict__ x, uint2* __restrict__ xb,
                          const float* __restrict__ W1, u16* __restrict__ w1hi,
                          u16* __restrict__ w1lo,
                          const float* __restrict__ W2, u16* __restrict__ w2hi,
                          u16* __restrict__ w2lo) {
    int i = blockIdx.x * 256 + threadIdx.x;
    float4 v = x[i];
    uint2 o;
    o.x = pack2(v.x, v.y);
    o.y = pack2(v.z, v.w);
    xb[i] = o;
    if (i < 32768) {  // W1: kc=0..3 (K=128), ct=0..15 (N=256)
        int j = i & 7;
        int l = (i >> 3) & 63;
        int ct = (i >> 9) & 15;
        int kc = i >> 13;
        int k = kc * 32 + (l >> 4) * 8 + j;
        int n = ct * 16 + (l & 15);
        float w = W1[k * D1 + n];
        u32 h = rne16(w);
        w1hi[i] = (u16)h;
        w1lo[i] = (u16)rne16(w - bf_lo(h));
    } else if (i < 32768 + 16384) {  // W2: kc=0..7 (K=256), nt=0..3 (N=64)
        int t = i - 32768;
        int j = t & 7;
        int l = (t >> 3) & 63;
        int nt = (t >> 9) & 3;
        int kc = t >> 11;
        int k = kc * 32 + (l >> 4) * 8 + j;
        int n = nt * 16 + (l & 15);
        float w = W2[k * D2 + n];
        u32 h = rne16(w);
        w2hi[t] = (u16)h;
        w2lo[t] = (u16)rne16(w - bf_lo(h));
    }
}

// ---------------- bucket edges by hedge-range and node-range ----------------
// 2048 edges/block; LDS histogram -> one global atomic per bucket per block ->
// pair writes land in ~32B runs (low line amplification).
__global__ void bucket_edges(const int* __restrict__ nidx, const int* __restrict__ hidx,
                             int* __restrict__ gcur_h, int* __restrict__ gcur_n,
                             u32* __restrict__ pairs_h, u32* __restrict__ pairs_n) {
    __shared__ int hist_h[NHB], hist_n[NNB];
    __shared__ int base_h[NHB], base_n[NNB];
    int tid = threadIdx.x;
    for (int t = tid; t < NHB; t += 256) hist_h[t] = 0;
    for (int t = tid; t < NNB; t += 256) hist_n[t] = 0;
    __syncthreads();
    int e0 = blockIdx.x * 2048 + tid * 8;
    int ns[8], hs_[8];
#pragma unroll
    for (int k = 0; k < 8; k++) {
        int e = e0 + k;
        if (e < NNZ) {
            ns[k] = nidx[e];
            hs_[k] = hidx[e];
            atomicAdd(&hist_h[hs_[k] / HBK], 1);
            atomicAdd(&hist_n[ns[k] / NBK], 1);
        } else {
            ns[k] = -1;
        }
    }
    __syncthreads();
    if (tid < NHB) base_h[tid] = atomicAdd(&gcur_h[tid], hist_h[tid]);
    for (int t = tid; t < NNB; t += 256) base_n[t] = atomicAdd(&gcur_n[t], hist_n[t]);
    __syncthreads();
    for (int t = tid; t < NHB; t += 256) hist_h[t] = 0;
    for (int t = tid; t < NNB; t += 256) hist_n[t] = 0;
    __syncthreads();
#pragma unroll
    for (int k = 0; k < 8; k++) {
        if (ns[k] >= 0) {
            int n = ns[k], h = hs_[k];
            int bh = h / HBK, bn = n / NBK;
            int s1 = base_h[bh] + atomicAdd(&hist_h[bh], 1);
            if (s1 < HCAP) pairs_h[bh * HCAP + s1] = ((u32)h << 16) | (u32)n;
            int s2 = base_n[bn] + atomicAdd(&hist_n[bn], 1);
            if (s2 < NCAP) pairs_n[bn * NCAP + s2] = ((u32)n << 16) | (u32)h;
        }
    }
}

// ---------------- build hedge adjacency rows in LDS, write coalesced ----------------
__global__ void build_adj_h(const u32* __restrict__ pairs_h, const int* __restrict__ gcur_h,
                            u16* __restrict__ adj_h, int* __restrict__ cur_h) {
    __shared__ u16 rows[HBK * SH];  // 10 KB
    __shared__ int cnt[HBK];
    int b = blockIdx.x, tid = threadIdx.x;
    if (tid < HBK) cnt[tid] = 0;
    __syncthreads();
    int np = gcur_h[b];
    if (np > HCAP) np = HCAP;
    for (int t = tid; t < np; t += 256) {
        u32 p = pairs_h[b * HCAP + t];
        int hl = (int)(p >> 16) - b * HBK;
        int s = atomicAdd(&cnt[hl], 1);
        if (s < SH) rows[hl * SH + s] = (u16)(p & 0xffff);
    }
    __syncthreads();
    u32* dst = (u32*)(adj_h + b * HBK * SH);
    const u32* srcl = (const u32*)rows;
    for (int t = tid; t < HBK * SH / 2; t += 256) dst[t] = srcl[t];
    if (tid < HBK) cur_h[b * HBK + tid] = cnt[tid];
}

// ---------------- build node adjacency rows in LDS, write coalesced ----------------
__global__ void build_adj_n(const u32* __restrict__ pairs_n, const int* __restrict__ gcur_n,
                            u16* __restrict__ adj_n, int* __restrict__ cur_n) {
    __shared__ u16 rows[NBK * SN];  // 12.8 KB
    __shared__ int cnt[NBK];
    int b = blockIdx.x, tid = threadIdx.x;
    if (tid < NBK) cnt[tid] = 0;
    __syncthreads();
    int np = gcur_n[b];
    if (np > NCAP) np = NCAP;
    for (int t = tid; t < np; t += 256) {
        u32 p = pairs_n[b * NCAP + t];
        int nl = (int)(p >> 16) - b * NBK;
        int s = atomicAdd(&cnt[nl], 1);
        if (s < SN) rows[nl * SN + s] = (u16)(p & 0xffff);
    }
    __syncthreads();
    u32* dst = (u32*)(adj_n + b * NBK * SN);
    const u32* srcl = (const u32*)rows;
    for (int t = tid; t < NBK * SN / 2; t += 256) dst[t] = srcl[t];
    if (tid < NBK) cur_n[b * NBK + tid] = cnt[tid];
}

// ---------------- bf16-source pull-gather, vec-adj, prefetch-8, 4 acc banks ----------------
template <int F, int S, bool BIAS_RELU, bool DST_BF16>
__global__ void gatherb(const uint4* __restrict__ src, const int* __restrict__ cur,
                        const u16* __restrict__ adj, const float4* __restrict__ bias,
                        void* __restrict__ dst, int nrows) {
    constexpr int L = F / 8;
    int gid = blockIdx.x * 256 + threadIdx.x;
    int row = gid / L;
    if (row >= nrows) return;
    int c = gid - row * L;
    int len = cur[row];
    int lenc = (len < S) ? len : S;
    int s = row * S, e = s + lenc;
    float a0[8] = {0,0,0,0,0,0,0,0}, a1[8] = {0,0,0,0,0,0,0,0};
    float a2[8] = {0,0,0,0,0,0,0,0}, a3[8] = {0,0,0,0,0,0,0,0};
    int j = s;
    for (; j + 7 < e; j += 8) {
        uint4 aa = *(const uint4*)(adj + j);   // 8 indices in one 16B load
        int i0 = aa.x & 0xffff, i1 = aa.x >> 16;
        int i2 = aa.y & 0xffff, i3 = aa.y >> 16;
        int i4 = aa.z & 0xffff, i5 = aa.z >> 16;
        int i6 = aa.w & 0xffff, i7 = aa.w >> 16;
        uint4 v0 = src[i0 * L + c];
        uint4 v1 = src[i1 * L + c];
        uint4 v2 = src[i2 * L + c];
        uint4 v3 = src[i3 * L + c];
        uint4 v4 = src[i4 * L + c];
        uint4 v5 = src[i5 * L + c];
        uint4 v6 = src[i6 * L + c];
        uint4 v7 = src[i7 * L + c];
        acc8(a0, v0); acc8(a1, v1); acc8(a2, v2); acc8(a3, v3);
        acc8(a0, v4); acc8(a1, v5); acc8(a2, v6); acc8(a3, v7);
    }
    for (; j < e; j++) {
        uint4 v = src[(int)adj[j] * L + c];
        acc8(a0, v);
    }
    float inv = (len > 0) ? 1.f / (float)len : 0.f;
    float r[8];
#pragma unroll
    for (int t = 0; t < 8; t++) r[t] = ((a0[t] + a1[t]) + (a2[t] + a3[t])) * inv;
    if (BIAS_RELU) {
        float4 b0 = bias[c * 2], b1v = bias[c * 2 + 1];
        r[0] = fmaxf(r[0] + b0.x, 0.f); r[1] = fmaxf(r[1] + b0.y, 0.f);
        r[2] = fmaxf(r[2] + b0.z, 0.f); r[3] = fmaxf(r[3] + b0.w, 0.f);
        r[4] = fmaxf(r[4] + b1v.x, 0.f); r[5] = fmaxf(r[5] + b1v.y, 0.f);
        r[6] = fmaxf(r[6] + b1v.z, 0.f); r[7] = fmaxf(r[7] + b1v.w, 0.f);
    }
    if (DST_BF16) {
        uint4 o;
        o.x = pack2(r[0], r[1]);
        o.y = pack2(r[2], r[3]);
        o.z = pack2(r[4], r[5]);
        o.w = pack2(r[6], r[7]);
        ((uint4*)dst)[row * L + c] = o;
    } else {
        float4* d = (float4*)dst;
        d[row * (F / 4) + c * 2]     = make_float4(r[0], r[1], r[2], r[3]);
        d[row * (F / 4) + c * 2 + 1] = make_float4(r[4], r[5], r[6], r[7]);
    }
}

// ---------------- fused node MLP: hw = relu(sb @ W1 + b1) @ W2  (MFMA) ----------------
#define HSTRIDE 264
__global__ void node_mlp(const uint4* __restrict__ sb4,
                         const short8* __restrict__ w1hi, const short8* __restrict__ w1lo,
                         const float* __restrict__ b1,
                         const short8* __restrict__ w2hi, const short8* __restrict__ w2lo,
                         u16* __restrict__ hw) {
    __shared__ u16 hs[16 * HSTRIDE];  // 8448 B
    int tid = threadIdx.x;
    int wave = tid >> 6;
    int lane = tid & 63;
    int node0 = blockIdx.x * 16;
    int m = lane & 15;
    int q = lane >> 4;
    short8 a[4];
    const uint4* srow = sb4 + (node0 + m) * 16 + q;
#pragma unroll
    for (int kc = 0; kc < 4; kc++) {
        uint4 t = srow[kc * 4];
        a[kc] = *(short8*)&t;
    }
#pragma unroll
    for (int i = 0; i < 4; i++) {
        int ct = wave * 4 + i;
        f32x4 acc = {0.f, 0.f, 0.f, 0.f};
#pragma unroll
        for (int kc = 0; kc < 4; kc++) {
            acc = __builtin_amdgcn_mfma_f32_16x16x32_bf16(a[kc], w1hi[(kc * 16 + ct) * 64 + lane], acc, 0, 0, 0);
            acc = __builtin_amdgcn_mfma_f32_16x16x32_bf16(a[kc], w1lo[(kc * 16 + ct) * 64 + lane], acc, 0, 0, 0);
        }
        int col = ct * 16 + m;
        float bc = b1[col];
#pragma unroll
        for (int r = 0; r < 4; r++) {
            float h = fmaxf(acc[r] + bc, 0.f);
            hs[(q * 4 + r) * HSTRIDE + col] = (u16)rne16(h);
        }
    }
    __syncthreads();
    f32x4 acc = {0.f, 0.f, 0.f, 0.f};
#pragma unroll
    for (int kc = 0; kc < 8; kc++) {
        short8 ah = *(const short8*)&hs[m * HSTRIDE + kc * 32 + q * 8];
        acc = __builtin_amdgcn_mfma_f32_16x16x32_bf16(ah, w2hi[(kc * 4 + wave) * 64 + lane], acc, 0, 0, 0);
        acc = __builtin_amdgcn_mfma_f32_16x16x32_bf16(ah, w2lo[(kc * 4 + wave) * 64 + lane], acc, 0, 0, 0);
    }
#pragma unroll
    for (int r = 0; r < 4; r++) {
        hw[(node0 + q * 4 + r) * D2 + wave * 16 + m] = (u16)rne16(acc[r]);
    }
}

extern "C" void kernel_launch(void* const* d_in, const int* in_sizes, int n_in,
                              void* d_out, int out_size, void* d_ws, size_t ws_size,
                              hipStream_t stream) {
    const float* x  = (const float*)d_in[0];
    const int* edge = (const int*)d_in[1];
    const int* nidx = edge;         // edge[0, :]
    const int* hidx = edge + NNZ;   // edge[1, :]
    const float* W1 = (const float*)d_in[2];
    const float* b1 = (const float*)d_in[3];
    const float* W2 = (const float*)d_in[4];
    const float* b2 = (const float*)d_in[5];
    float* out = (float*)d_out;

    // ---- workspace layout (all chunks 16B-aligned) ----
    u16* xb     = (u16*)d_ws;                 // 50000*128 u16 = 6,400,000
    u16* aggxb  = xb + N_NODES * IN_C;        // 5000*128  u16 = 640,000
    u16* sb     = aggxb + N_HEDGES * IN_C;    // 50000*128 u16 = 6,400,000
    u16* hwb    = sb + N_NODES * IN_C;        // 50000*64  u16 = 3,200,000
    u16* e2b    = hwb + N_NODES * D2;         // 5000*64   u16 = 320,000
    u16* w1hi   = e2b + N_HEDGES * D2;        // 32768 u16
    u16* w1lo   = w1hi + 32768;               // 32768 u16
    u16* w2hi   = w1lo + 32768;               // 16384 u16
    u16* w2lo   = w2hi + 16384;               // 16384 u16
    u16* adj_n  = w2lo + 16384;               // 50000*64 u16 = 3,200,000
    u16* adj_h  = adj_n + N_NODES * SN;       // 5000*256 u16 = 1,280,000
    u32* pairs_h = (u32*)(adj_h + N_HEDGES * SH); // 250*4096 u32 = 4 MB
    u32* pairs_n = pairs_h + NHB * HCAP;          // 500*2048 u32 = 4 MB
    int* cur_n  = (int*)(pairs_n + NNB * NCAP);   // 50000 (written by build)
    int* cur_h  = cur_n + N_NODES;                // 5000  (written by build)
    int* gcur_h = cur_h + N_HEDGES;               // 256 (zeroed)
    int* gcur_n = gcur_h + 256;                   // 512 (zeroed)
    // total ≈ 30 MB

    hipMemsetAsync(gcur_h, 0, (256 + 512) * sizeof(int), stream);

    cast_pack<<<N_NODES * IN_C / 4 / 256, 256, 0, stream>>>(
        (const float4*)x, (uint2*)xb, W1, w1hi, w1lo, W2, w2hi, w2lo);

    bucket_edges<<<(NNZ + 2047) / 2048, 256, 0, stream>>>(
        nidx, hidx, gcur_h, gcur_n, pairs_h, pairs_n);
    build_adj_h<<<NHB, 256, 0, stream>>>(pairs_h, gcur_h, adj_h, cur_h);
    build_adj_n<<<NNB, 256, 0, stream>>>(pairs_n, gcur_n, adj_n, cur_n);

    // aggxb = Binv * gather_h(xb)   [5000 x 128 bf16]
    gatherb<IN_C, SH, false, true><<<(N_HEDGES * (IN_C / 8) + 255) / 256, 256, 0, stream>>>(
        (const uint4*)xb, cur_h, adj_h, nullptr, aggxb, N_HEDGES);
    // sb = Dinv * gather_n(aggxb)   [50000 x 128 bf16]   (W1 commuted to the right)
    gatherb<IN_C, SN, false, true><<<(N_NODES * (IN_C / 8) + 255) / 256, 256, 0, stream>>>(
        (const uint4*)aggxb, cur_n, adj_n, nullptr, sb, N_NODES);

    // hw = relu(sb @ W1 + b1) @ W2   [50000 x 64 bf16]  (fused MFMA)
    node_mlp<<<N_NODES / 16, 256, 0, stream>>>(
        (const uint4*)sb, (const short8*)w1hi, (const short8*)w1lo, b1,
        (const short8*)w2hi, (const short8*)w2lo, hwb);

    // layer 2: e2b = Binv * gather_h(hwb); out = relu(Dinv * gather_n(e2b) + b2)
    gatherb<D2, SH, false, true><<<(N_HEDGES * (D2 / 8) + 255) / 256, 256, 0, stream>>>(
        (const uint4*)hwb, cur_h, adj_h, nullptr, e2b, N_HEDGES);
    gatherb<D2, SN, true, false><<<(N_NODES * (D2 / 8) + 255) / 256, 256, 0, stream>>>(
        (const uint4*)e2b, cur_n, adj_n, (const float4*)b2, out, N_NODES);
}

// Round 15
// 228.166 us; speedup vs baseline: 1.4293x; 1.0885x over previous
//
#include <hip/hip_runtime.h>

#define N_NODES 50000
#define N_HEDGES 5000
#define NNZ 800000
#define IN_C 128
#define D1 256
#define D2 64
#define SN 64    // fixed stride: hedges per node row (deg mean 16, 12 sigma safe)
#define SH 256   // fixed stride: nodes per hedge row (deg mean 160, 7.6 sigma safe)

// bucketed adjacency build
#define HBK 20     // hedges per bucket
#define NHB 250    // hedge buckets
#define HCAP 4096  // pair capacity per hedge bucket (mean 3200, 16 sigma)
#define NBK 100    // nodes per bucket
#define NNB 500    // node buckets
#define NCAP 2048  // pair capacity per node bucket (mean 1600, 11 sigma)
#define BKT_BLOCKS ((NNZ + 2047) / 2048)   // 391

typedef unsigned int u32;
typedef unsigned short u16;
typedef __attribute__((ext_vector_type(8))) short short8;
typedef __attribute__((ext_vector_type(4))) float f32x4;

// ---- bf16 helpers: storage bf16, math f32 ----
__device__ __forceinline__ float bf_lo(u32 u) { return __uint_as_float(u << 16); }
__device__ __forceinline__ float bf_hi(u32 u) { return __uint_as_float(u & 0xffff0000u); }
__device__ __forceinline__ u32 rne16(float f) {
    u32 u = __float_as_uint(f);
    return (u + 0x7fffu + ((u >> 16) & 1u)) >> 16;
}
__device__ __forceinline__ u32 pack2(float a, float b) {
    return rne16(a) | (rne16(b) << 16);
}
__device__ __forceinline__ void acc8(float* a, uint4 v) {
    a[0] += bf_lo(v.x); a[1] += bf_hi(v.x);
    a[2] += bf_lo(v.y); a[3] += bf_hi(v.y);
    a[4] += bf_lo(v.z); a[5] += bf_hi(v.z);
    a[6] += bf_lo(v.w); a[7] += bf_hi(v.w);
}

// ---------------- fused: cast x->bf16 + pack W1/W2 + bucket edges ----------------
// grid 6250 blocks: all cast; blocks < BKT_BLOCKS also bucket 2048 edges each.
__global__ void cast_bucket(const float4* __restrict__ x, uint2* __restrict__ xb,
                            const float* __restrict__ W1, u16* __restrict__ w1hi,
                            u16* __restrict__ w1lo,
                            const float* __restrict__ W2, u16* __restrict__ w2hi,
                            u16* __restrict__ w2lo,
                            const int* __restrict__ nidx, const int* __restrict__ hidx,
                            int* __restrict__ gcur_h, int* __restrict__ gcur_n,
                            u32* __restrict__ pairs_h, u32* __restrict__ pairs_n) {
    __shared__ int hist_h[NHB], hist_n[NNB];
    __shared__ int base_h[NHB], base_n[NNB];
    int tid = threadIdx.x;
    int i = blockIdx.x * 256 + tid;
    float4 v = x[i];
    uint2 o;
    o.x = pack2(v.x, v.y);
    o.y = pack2(v.z, v.w);
    xb[i] = o;
    if (i < 32768) {  // W1: kc=0..3 (K=128), ct=0..15 (N=256)
        int j = i & 7;
        int l = (i >> 3) & 63;
        int ct = (i >> 9) & 15;
        int kc = i >> 13;
        int k = kc * 32 + (l >> 4) * 8 + j;
        int n = ct * 16 + (l & 15);
        float w = W1[k * D1 + n];
        u32 h = rne16(w);
        w1hi[i] = (u16)h;
        w1lo[i] = (u16)rne16(w - bf_lo(h));
    } else if (i < 32768 + 16384) {  // W2: kc=0..7 (K=256), nt=0..3 (N=64)
        int t = i - 32768;
        int j = t & 7;
        int l = (t >> 3) & 63;
        int nt = (t >> 9) & 3;
        int kc = t >> 11;
        int k = kc * 32 + (l >> 4) * 8 + j;
        int n = nt * 16 + (l & 15);
        float w = W2[k * D2 + n];
        u32 h = rne16(w);
        w2hi[t] = (u16)h;
        w2lo[t] = (u16)rne16(w - bf_lo(h));
    }
    if (blockIdx.x >= BKT_BLOCKS) return;
    for (int t = tid; t < NHB; t += 256) hist_h[t] = 0;
    for (int t = tid; t < NNB; t += 256) hist_n[t] = 0;
    __syncthreads();
    int e0 = blockIdx.x * 2048 + tid * 8;
    int ns[8], hs_[8];
#pragma unroll
    for (int k = 0; k < 8; k++) {
        int e = e0 + k;
        if (e < NNZ) {
            ns[k] = nidx[e];
            hs_[k] = hidx[e];
            atomicAdd(&hist_h[hs_[k] / HBK], 1);
            atomicAdd(&hist_n[ns[k] / NBK], 1);
        } else {
            ns[k] = -1;
        }
    }
    __syncthreads();
    if (tid < NHB) base_h[tid] = atomicAdd(&gcur_h[tid], hist_h[tid]);
    for (int t = tid; t < NNB; t += 256) base_n[t] = atomicAdd(&gcur_n[t], hist_n[t]);
    __syncthreads();
    for (int t = tid; t < NHB; t += 256) hist_h[t] = 0;
    for (int t = tid; t < NNB; t += 256) hist_n[t] = 0;
    __syncthreads();
#pragma unroll
    for (int k = 0; k < 8; k++) {
        if (ns[k] >= 0) {
            int n = ns[k], h = hs_[k];
            int bh = h / HBK, bn = n / NBK;
            int s1 = base_h[bh] + atomicAdd(&hist_h[bh], 1);
            if (s1 < HCAP) pairs_h[bh * HCAP + s1] = ((u32)h << 16) | (u32)n;
            int s2 = base_n[bn] + atomicAdd(&hist_n[bn], 1);
            if (s2 < NCAP) pairs_n[bn * NCAP + s2] = ((u32)n << 16) | (u32)h;
        }
    }
}

// ---------------- build adjacency rows in LDS, write coalesced (both sides) ----------------
// blocks 0..NHB-1: hedge buckets; blocks NHB..NHB+NNB-1: node buckets.
__global__ void build_adj(const u32* __restrict__ pairs_h, const int* __restrict__ gcur_h,
                          u16* __restrict__ adj_h, int* __restrict__ cur_h,
                          const u32* __restrict__ pairs_n, const int* __restrict__ gcur_n,
                          u16* __restrict__ adj_n, int* __restrict__ cur_n) {
    __shared__ u16 rows[NBK * SN];  // 12.8 KB (>= HBK*SH = 10.24 KB)
    __shared__ int cnt[NBK];        // >= HBK
    int tid = threadIdx.x;
    if (blockIdx.x < NHB) {
        int b = blockIdx.x;
        if (tid < HBK) cnt[tid] = 0;
        __syncthreads();
        int np = gcur_h[b];
        if (np > HCAP) np = HCAP;
        for (int t = tid; t < np; t += 256) {
            u32 p = pairs_h[b * HCAP + t];
            int hl = (int)(p >> 16) - b * HBK;
            int s = atomicAdd(&cnt[hl], 1);
            if (s < SH) rows[hl * SH + s] = (u16)(p & 0xffff);
        }
        __syncthreads();
        u32* dst = (u32*)(adj_h + b * HBK * SH);
        const u32* srcl = (const u32*)rows;
        for (int t = tid; t < HBK * SH / 2; t += 256) dst[t] = srcl[t];
        if (tid < HBK) cur_h[b * HBK + tid] = cnt[tid];
    } else {
        int b = blockIdx.x - NHB;
        if (tid < NBK) cnt[tid] = 0;
        __syncthreads();
        int np = gcur_n[b];
        if (np > NCAP) np = NCAP;
        for (int t = tid; t < np; t += 256) {
            u32 p = pairs_n[b * NCAP + t];
            int nl = (int)(p >> 16) - b * NBK;
            int s = atomicAdd(&cnt[nl], 1);
            if (s < SN) rows[nl * SN + s] = (u16)(p & 0xffff);
        }
        __syncthreads();
        u32* dst = (u32*)(adj_n + b * NBK * SN);
        const u32* srcl = (const u32*)rows;
        for (int t = tid; t < NBK * SN / 2; t += 256) dst[t] = srcl[t];
        if (tid < NBK) cur_n[b * NBK + tid] = cnt[tid];
    }
}

// ---------------- bf16-source pull-gather, vec-adj, prefetch-8, 4 acc banks ----------------
template <int F, int S, bool BIAS_RELU, bool DST_BF16>
__global__ void gatherb(const uint4* __restrict__ src, const int* __restrict__ cur,
                        const u16* __restrict__ adj, const float4* __restrict__ bias,
                        void* __restrict__ dst, int nrows) {
    constexpr int L = F / 8;
    int gid = blockIdx.x * 256 + threadIdx.x;
    int row = gid / L;
    if (row >= nrows) return;
    int c = gid - row * L;
    int len = cur[row];
    int lenc = (len < S) ? len : S;
    int s = row * S, e = s + lenc;
    float a0[8] = {0,0,0,0,0,0,0,0}, a1[8] = {0,0,0,0,0,0,0,0};
    float a2[8] = {0,0,0,0,0,0,0,0}, a3[8] = {0,0,0,0,0,0,0,0};
    int j = s;
    for (; j + 7 < e; j += 8) {
        uint4 aa = *(const uint4*)(adj + j);
        int i0 = aa.x & 0xffff, i1 = aa.x >> 16;
        int i2 = aa.y & 0xffff, i3 = aa.y >> 16;
        int i4 = aa.z & 0xffff, i5 = aa.z >> 16;
        int i6 = aa.w & 0xffff, i7 = aa.w >> 16;
        uint4 v0 = src[i0 * L + c];
        uint4 v1 = src[i1 * L + c];
        uint4 v2 = src[i2 * L + c];
        uint4 v3 = src[i3 * L + c];
        uint4 v4 = src[i4 * L + c];
        uint4 v5 = src[i5 * L + c];
        uint4 v6 = src[i6 * L + c];
        uint4 v7 = src[i7 * L + c];
        acc8(a0, v0); acc8(a1, v1); acc8(a2, v2); acc8(a3, v3);
        acc8(a0, v4); acc8(a1, v5); acc8(a2, v6); acc8(a3, v7);
    }
    for (; j < e; j++) {
        uint4 v = src[(int)adj[j] * L + c];
        acc8(a0, v);
    }
    float inv = (len > 0) ? 1.f / (float)len : 0.f;
    float r[8];
#pragma unroll
    for (int t = 0; t < 8; t++) r[t] = ((a0[t] + a1[t]) + (a2[t] + a3[t])) * inv;
    if (BIAS_RELU) {
        float4 b0 = bias[c * 2], b1v = bias[c * 2 + 1];
        r[0] = fmaxf(r[0] + b0.x, 0.f); r[1] = fmaxf(r[1] + b0.y, 0.f);
        r[2] = fmaxf(r[2] + b0.z, 0.f); r[3] = fmaxf(r[3] + b0.w, 0.f);
        r[4] = fmaxf(r[4] + b1v.x, 0.f); r[5] = fmaxf(r[5] + b1v.y, 0.f);
        r[6] = fmaxf(r[6] + b1v.z, 0.f); r[7] = fmaxf(r[7] + b1v.w, 0.f);
    }
    if (DST_BF16) {
        uint4 o;
        o.x = pack2(r[0], r[1]);
        o.y = pack2(r[2], r[3]);
        o.z = pack2(r[4], r[5]);
        o.w = pack2(r[6], r[7]);
        ((uint4*)dst)[row * L + c] = o;
    } else {
        float4* d = (float4*)dst;
        d[row * (F / 4) + c * 2]     = make_float4(r[0], r[1], r[2], r[3]);
        d[row * (F / 4) + c * 2 + 1] = make_float4(r[4], r[5], r[6], r[7]);
    }
}

// ---------------- fused: sb = Dinv*gather_n(aggxb); hw = relu(sb@W1+b1)@W2 ----------------
// 16 nodes/block, 256 threads. Gather layout: thread = (node_local<<4) | c, c = uint4 col.
// sb staged in LDS (stride 136 u16: 16B-aligned, 2-way banks = free), then 2 MFMA phases.
#define SB_STRIDE 136
#define HSTRIDE 264
__global__ void gather_mlp(const uint4* __restrict__ aggxb4, const int* __restrict__ cur_n,
                           const u16* __restrict__ adj_n,
                           const short8* __restrict__ w1hi, const short8* __restrict__ w1lo,
                           const float* __restrict__ b1,
                           const short8* __restrict__ w2hi, const short8* __restrict__ w2lo,
                           u16* __restrict__ hw) {
    __shared__ u16 sbs[16 * SB_STRIDE];  // 4352 B
    __shared__ u16 hs[16 * HSTRIDE];     // 8448 B
    int tid = threadIdx.x;
    int node0 = blockIdx.x * 16;
    {
        int nl = tid >> 4;      // node local 0..15
        int c = tid & 15;       // uint4 column 0..15
        int node = node0 + nl;
        int len = cur_n[node];
        int lenc = (len < SN) ? len : SN;
        const u16* adj = adj_n + node * SN;
        float a0[8] = {0,0,0,0,0,0,0,0}, a1[8] = {0,0,0,0,0,0,0,0};
        float a2[8] = {0,0,0,0,0,0,0,0}, a3[8] = {0,0,0,0,0,0,0,0};
        int j = 0;
        for (; j + 7 < lenc; j += 8) {
            uint4 aa = *(const uint4*)(adj + j);
            int i0 = aa.x & 0xffff, i1 = aa.x >> 16;
            int i2 = aa.y & 0xffff, i3 = aa.y >> 16;
            int i4 = aa.z & 0xffff, i5 = aa.z >> 16;
            int i6 = aa.w & 0xffff, i7 = aa.w >> 16;
            uint4 v0 = aggxb4[i0 * 16 + c];
            uint4 v1 = aggxb4[i1 * 16 + c];
            uint4 v2 = aggxb4[i2 * 16 + c];
            uint4 v3 = aggxb4[i3 * 16 + c];
            uint4 v4 = aggxb4[i4 * 16 + c];
            uint4 v5 = aggxb4[i5 * 16 + c];
            uint4 v6 = aggxb4[i6 * 16 + c];
            uint4 v7 = aggxb4[i7 * 16 + c];
            acc8(a0, v0); acc8(a1, v1); acc8(a2, v2); acc8(a3, v3);
            acc8(a0, v4); acc8(a1, v5); acc8(a2, v6); acc8(a3, v7);
        }
        for (; j < lenc; j++) {
            uint4 v = aggxb4[(int)adj[j] * 16 + c];
            acc8(a0, v);
        }
        float inv = (len > 0) ? 1.f / (float)len : 0.f;
        float r[8];
#pragma unroll
        for (int t = 0; t < 8; t++) r[t] = ((a0[t] + a1[t]) + (a2[t] + a3[t])) * inv;
        u32* dstl = (u32*)&sbs[nl * SB_STRIDE + c * 8];
        dstl[0] = pack2(r[0], r[1]);
        dstl[1] = pack2(r[2], r[3]);
        dstl[2] = pack2(r[4], r[5]);
        dstl[3] = pack2(r[6], r[7]);
    }
    __syncthreads();
    int wave = tid >> 6;
    int lane = tid & 63;
    int m = lane & 15;
    int q = lane >> 4;
    short8 a[4];
#pragma unroll
    for (int kc = 0; kc < 4; kc++)
        a[kc] = *(const short8*)&sbs[m * SB_STRIDE + kc * 32 + q * 8];
#pragma unroll
    for (int i = 0; i < 4; i++) {
        int ct = wave * 4 + i;
        f32x4 acc = {0.f, 0.f, 0.f, 0.f};
#pragma unroll
        for (int kc = 0; kc < 4; kc++) {
            acc = __builtin_amdgcn_mfma_f32_16x16x32_bf16(a[kc], w1hi[(kc * 16 + ct) * 64 + lane], acc, 0, 0, 0);
            acc = __builtin_amdgcn_mfma_f32_16x16x32_bf16(a[kc], w1lo[(kc * 16 + ct) * 64 + lane], acc, 0, 0, 0);
        }
        int col = ct * 16 + m;   // C layout: col = lane&15, row = q*4+r
        float bc = b1[col];
#pragma unroll
        for (int r = 0; r < 4; r++) {
            float h = fmaxf(acc[r] + bc, 0.f);
            hs[(q * 4 + r) * HSTRIDE + col] = (u16)rne16(h);
        }
    }
    __syncthreads();
    f32x4 acc = {0.f, 0.f, 0.f, 0.f};
#pragma unroll
    for (int kc = 0; kc < 8; kc++) {
        short8 ah = *(const short8*)&hs[m * HSTRIDE + kc * 32 + q * 8];
        acc = __builtin_amdgcn_mfma_f32_16x16x32_bf16(ah, w2hi[(kc * 4 + wave) * 64 + lane], acc, 0, 0, 0);
        acc = __builtin_amdgcn_mfma_f32_16x16x32_bf16(ah, w2lo[(kc * 4 + wave) * 64 + lane], acc, 0, 0, 0);
    }
#pragma unroll
    for (int r = 0; r < 4; r++) {
        hw[(node0 + q * 4 + r) * D2 + wave * 16 + m] = (u16)rne16(acc[r]);
    }
}

extern "C" void kernel_launch(void* const* d_in, const int* in_sizes, int n_in,
                              void* d_out, int out_size, void* d_ws, size_t ws_size,
                              hipStream_t stream) {
    const float* x  = (const float*)d_in[0];
    const int* edge = (const int*)d_in[1];
    const int* nidx = edge;         // edge[0, :]
    const int* hidx = edge + NNZ;   // edge[1, :]
    const float* W1 = (const float*)d_in[2];
    const float* b1 = (const float*)d_in[3];
    const float* W2 = (const float*)d_in[4];
    const float* b2 = (const float*)d_in[5];
    float* out = (float*)d_out;

    // ---- workspace layout (all chunks 16B-aligned) ----
    u16* xb     = (u16*)d_ws;                 // 50000*128 u16 = 6,400,000
    u16* aggxb  = xb + N_NODES * IN_C;        // 5000*128  u16 = 640,000
    u16* hwb    = aggxb + N_HEDGES * IN_C;    // 50000*64  u16 = 3,200,000
    u16* e2b    = hwb + N_NODES * D2;         // 5000*64   u16 = 320,000
    u16* w1hi   = e2b + N_HEDGES * D2;        // 32768 u16
    u16* w1lo   = w1hi + 32768;               // 32768 u16
    u16* w2hi   = w1lo + 32768;               // 16384 u16
    u16* w2lo   = w2hi + 16384;               // 16384 u16
    u16* adj_n  = w2lo + 16384;               // 50000*64 u16 = 3,200,000
    u16* adj_h  = adj_n + N_NODES * SN;       // 5000*256 u16 = 1,280,000
    u32* pairs_h = (u32*)(adj_h + N_HEDGES * SH); // 250*4096 u32 = 4 MB
    u32* pairs_n = pairs_h + NHB * HCAP;          // 500*2048 u32 = 4 MB
    int* cur_n  = (int*)(pairs_n + NNB * NCAP);   // 50000 (written by build)
    int* cur_h  = cur_n + N_NODES;                // 5000  (written by build)
    int* gcur_h = cur_h + N_HEDGES;               // 256 (zeroed)
    int* gcur_n = gcur_h + 256;                   // 512 (zeroed)
    // total ≈ 17 MB

    hipMemsetAsync(gcur_h, 0, (256 + 512) * sizeof(int), stream);

    // fused: cast + W-pack + bucket
    cast_bucket<<<N_NODES * IN_C / 4 / 256, 256, 0, stream>>>(
        (const float4*)x, (uint2*)xb, W1, w1hi, w1lo, W2, w2hi, w2lo,
        nidx, hidx, gcur_h, gcur_n, pairs_h, pairs_n);

    build_adj<<<NHB + NNB, 256, 0, stream>>>(pairs_h, gcur_h, adj_h, cur_h,
                                             pairs_n, gcur_n, adj_n, cur_n);

    // aggxb = Binv * gather_h(xb)   [5000 x 128 bf16]
    gatherb<IN_C, SH, false, true><<<(N_HEDGES * (IN_C / 8) + 255) / 256, 256, 0, stream>>>(
        (const uint4*)xb, cur_h, adj_h, nullptr, aggxb, N_HEDGES);

    // fused: sb = Dinv*gather_n(aggxb); hw = relu(sb@W1+b1)@W2   [50000 x 64 bf16]
    gather_mlp<<<N_NODES / 16, 256, 0, stream>>>(
        (const uint4*)aggxb, cur_n, adj_n,
        (const short8*)w1hi, (const short8*)w1lo, b1,
        (const short8*)w2hi, (const short8*)w2lo, hwb);

    // layer 2: e2b = Binv * gather_h(hwb); out = relu(Dinv * gather_n(e2b) + b2)
    gatherb<D2, SH, false, true><<<(N_HEDGES * (D2 / 8) + 255) / 256, 256, 0, stream>>>(
        (const uint4*)hwb, cur_h, adj_h, nullptr, e2b, N_HEDGES);
    gatherb<D2, SN, true, false><<<(N_NODES * (D2 / 8) + 255) / 256, 256, 0, stream>>>(
        (const uint4*)e2b, cur_n, adj_n, (const float4*)b2, out, N_NODES);
}

// Round 16
// 219.116 us; speedup vs baseline: 1.4883x; 1.0413x over previous
//
#include <hip/hip_runtime.h>

#define N_NODES 50000
#define N_HEDGES 5000
#define NNZ 800000
#define IN_C 128
#define D1 256
#define D2 64
#define SN 64    // fixed stride: hedges per node row (deg mean 16, 12 sigma safe)
#define SH 256   // fixed stride: nodes per hedge row (deg mean 160, 7.6 sigma safe)

// bucketed adjacency build
#define HBK 20     // hedges per bucket
#define NHB 250    // hedge buckets
#define HCAP 4096  // pair capacity per hedge bucket (mean 3200, 16 sigma)
#define NBK 100    // nodes per bucket
#define NNB 500    // node buckets
#define NCAP 2048  // pair capacity per node bucket (mean 1600, 11 sigma)
#define BKT_BLOCKS ((NNZ + 2047) / 2048)   // 391

typedef unsigned int u32;
typedef unsigned short u16;
typedef __attribute__((ext_vector_type(8))) short short8;
typedef __attribute__((ext_vector_type(4))) float f32x4;

// ---- bf16 helpers: storage bf16, math f32 ----
__device__ __forceinline__ float bf_lo(u32 u) { return __uint_as_float(u << 16); }
__device__ __forceinline__ float bf_hi(u32 u) { return __uint_as_float(u & 0xffff0000u); }
__device__ __forceinline__ u32 rne16(float f) {
    u32 u = __float_as_uint(f);
    return (u + 0x7fffu + ((u >> 16) & 1u)) >> 16;
}
__device__ __forceinline__ u32 pack2(float a, float b) {
    return rne16(a) | (rne16(b) << 16);
}
__device__ __forceinline__ void acc8(float* a, uint4 v) {
    a[0] += bf_lo(v.x); a[1] += bf_hi(v.x);
    a[2] += bf_lo(v.y); a[3] += bf_hi(v.y);
    a[4] += bf_lo(v.z); a[5] += bf_hi(v.z);
    a[6] += bf_lo(v.w); a[7] += bf_hi(v.w);
}

// ---------------- fused: cast x->bf16 + pack W1/W2 + bucket edges ----------------
__global__ void cast_bucket(const float4* __restrict__ x, uint2* __restrict__ xb,
                            const float* __restrict__ W1, u16* __restrict__ w1hi,
                            u16* __restrict__ w1lo,
                            const float* __restrict__ W2, u16* __restrict__ w2hi,
                            u16* __restrict__ w2lo,
                            const int* __restrict__ nidx, const int* __restrict__ hidx,
                            int* __restrict__ gcur_h, int* __restrict__ gcur_n,
                            u32* __restrict__ pairs_h, u32* __restrict__ pairs_n) {
    __shared__ int hist_h[NHB], hist_n[NNB];
    __shared__ int base_h[NHB], base_n[NNB];
    int tid = threadIdx.x;
    int i = blockIdx.x * 256 + tid;
    float4 v = x[i];
    uint2 o;
    o.x = pack2(v.x, v.y);
    o.y = pack2(v.z, v.w);
    xb[i] = o;
    if (i < 32768) {  // W1: kc=0..3 (K=128), ct=0..15 (N=256)
        int j = i & 7;
        int l = (i >> 3) & 63;
        int ct = (i >> 9) & 15;
        int kc = i >> 13;
        int k = kc * 32 + (l >> 4) * 8 + j;
        int n = ct * 16 + (l & 15);
        float w = W1[k * D1 + n];
        u32 h = rne16(w);
        w1hi[i] = (u16)h;
        w1lo[i] = (u16)rne16(w - bf_lo(h));
    } else if (i < 32768 + 16384) {  // W2: kc=0..7 (K=256), nt=0..3 (N=64)
        int t = i - 32768;
        int j = t & 7;
        int l = (t >> 3) & 63;
        int nt = (t >> 9) & 3;
        int kc = t >> 11;
        int k = kc * 32 + (l >> 4) * 8 + j;
        int n = nt * 16 + (l & 15);
        float w = W2[k * D2 + n];
        u32 h = rne16(w);
        w2hi[t] = (u16)h;
        w2lo[t] = (u16)rne16(w - bf_lo(h));
    }
    if (blockIdx.x >= BKT_BLOCKS) return;
    for (int t = tid; t < NHB; t += 256) hist_h[t] = 0;
    for (int t = tid; t < NNB; t += 256) hist_n[t] = 0;
    __syncthreads();
    int e0 = blockIdx.x * 2048 + tid * 8;
    int ns[8], hs_[8];
#pragma unroll
    for (int k = 0; k < 8; k++) {
        int e = e0 + k;
        if (e < NNZ) {
            ns[k] = nidx[e];
            hs_[k] = hidx[e];
            atomicAdd(&hist_h[hs_[k] / HBK], 1);
            atomicAdd(&hist_n[ns[k] / NBK], 1);
        } else {
            ns[k] = -1;
        }
    }
    __syncthreads();
    if (tid < NHB) base_h[tid] = atomicAdd(&gcur_h[tid], hist_h[tid]);
    for (int t = tid; t < NNB; t += 256) base_n[t] = atomicAdd(&gcur_n[t], hist_n[t]);
    __syncthreads();
    for (int t = tid; t < NHB; t += 256) hist_h[t] = 0;
    for (int t = tid; t < NNB; t += 256) hist_n[t] = 0;
    __syncthreads();
#pragma unroll
    for (int k = 0; k < 8; k++) {
        if (ns[k] >= 0) {
            int n = ns[k], h = hs_[k];
            int bh = h / HBK, bn = n / NBK;
            int s1 = base_h[bh] + atomicAdd(&hist_h[bh], 1);
            if (s1 < HCAP) pairs_h[bh * HCAP + s1] = ((u32)h << 16) | (u32)n;
            int s2 = base_n[bn] + atomicAdd(&hist_n[bn], 1);
            if (s2 < NCAP) pairs_n[bn * NCAP + s2] = ((u32)n << 16) | (u32)h;
        }
    }
}

// ---------------- build adjacency rows in LDS, write coalesced (both sides) ----------------
__global__ void build_adj(const u32* __restrict__ pairs_h, const int* __restrict__ gcur_h,
                          u16* __restrict__ adj_h, int* __restrict__ cur_h,
                          const u32* __restrict__ pairs_n, const int* __restrict__ gcur_n,
                          u16* __restrict__ adj_n, int* __restrict__ cur_n) {
    __shared__ u16 rows[NBK * SN];  // 12.8 KB (>= HBK*SH = 10.24 KB)
    __shared__ int cnt[NBK];        // >= HBK
    int tid = threadIdx.x;
    if (blockIdx.x < NHB) {
        int b = blockIdx.x;
        if (tid < HBK) cnt[tid] = 0;
        __syncthreads();
        int np = gcur_h[b];
        if (np > HCAP) np = HCAP;
        for (int t = tid; t < np; t += 256) {
            u32 p = pairs_h[b * HCAP + t];
            int hl = (int)(p >> 16) - b * HBK;
            int s = atomicAdd(&cnt[hl], 1);
            if (s < SH) rows[hl * SH + s] = (u16)(p & 0xffff);
        }
        __syncthreads();
        u32* dst = (u32*)(adj_h + b * HBK * SH);
        const u32* srcl = (const u32*)rows;
        for (int t = tid; t < HBK * SH / 2; t += 256) dst[t] = srcl[t];
        if (tid < HBK) cur_h[b * HBK + tid] = cnt[tid];
    } else {
        int b = blockIdx.x - NHB;
        if (tid < NBK) cnt[tid] = 0;
        __syncthreads();
        int np = gcur_n[b];
        if (np > NCAP) np = NCAP;
        for (int t = tid; t < np; t += 256) {
            u32 p = pairs_n[b * NCAP + t];
            int nl = (int)(p >> 16) - b * NBK;
            int s = atomicAdd(&cnt[nl], 1);
            if (s < SN) rows[nl * SN + s] = (u16)(p & 0xffff);
        }
        __syncthreads();
        u32* dst = (u32*)(adj_n + b * NBK * SN);
        const u32* srcl = (const u32*)rows;
        for (int t = tid; t < NBK * SN / 2; t += 256) dst[t] = srcl[t];
        if (tid < NBK) cur_n[b * NBK + tid] = cnt[tid];
    }
}

// ---------------- split-K hedge gather: L*SPLIT threads/row, LDS combine ----------------
// Output always bf16; Binv scale fused. SPLIT segments of S/SPLIT member slots.
template <int F, int S, int SPLIT>
__global__ void gather_split(const uint4* __restrict__ src, const int* __restrict__ cur,
                             const u16* __restrict__ adj, uint4* __restrict__ dst,
                             int nrows) {
    constexpr int L = F / 8;
    constexpr int TR = L * SPLIT;       // threads per row
    constexpr int RB = 256 / TR;        // rows per block
    constexpr int CHUNK = S / SPLIT;
    __shared__ float part[RB][SPLIT][8];
    int tid = threadIdx.x;
    int rl = tid / TR;
    int seg = (tid % TR) / L;
    int c = tid % L;
    int row = blockIdx.x * RB + rl;
    bool valid = row < nrows;
    int len = valid ? cur[row] : 0;
    int lenc = (len < S) ? len : S;
    int js = seg * CHUNK;
    int je = (lenc < js + CHUNK) ? lenc : (js + CHUNK);
    float a0[8] = {0,0,0,0,0,0,0,0}, a1[8] = {0,0,0,0,0,0,0,0};
    float a2[8] = {0,0,0,0,0,0,0,0}, a3[8] = {0,0,0,0,0,0,0,0};
    if (valid) {
        const u16* arow = adj + row * S;
        int j = js;
        for (; j + 7 < je; j += 8) {
            uint4 aa = *(const uint4*)(arow + j);
            int i0 = aa.x & 0xffff, i1 = aa.x >> 16;
            int i2 = aa.y & 0xffff, i3 = aa.y >> 16;
            int i4 = aa.z & 0xffff, i5 = aa.z >> 16;
            int i6 = aa.w & 0xffff, i7 = aa.w >> 16;
            uint4 v0 = src[i0 * L + c];
            uint4 v1 = src[i1 * L + c];
            uint4 v2 = src[i2 * L + c];
            uint4 v3 = src[i3 * L + c];
            uint4 v4 = src[i4 * L + c];
            uint4 v5 = src[i5 * L + c];
            uint4 v6 = src[i6 * L + c];
            uint4 v7 = src[i7 * L + c];
            acc8(a0, v0); acc8(a1, v1); acc8(a2, v2); acc8(a3, v3);
            acc8(a0, v4); acc8(a1, v5); acc8(a2, v6); acc8(a3, v7);
        }
        for (; j < je; j++) {
            uint4 v = src[(int)arow[j] * L + c];
            acc8(a0, v);
        }
    }
    // per-seg partial -> LDS (only seg's own c slots matter; all threads write)
    // layout trick: each (rl, seg) owns part[rl][seg][0..7] per c — but c varies;
    // we reduce across seg for fixed c, so store at [rl][seg] indexed by c via
    // re-purposing: threads with same (rl,c) different seg use distinct [seg] rows.
    // We need per-(rl,c,seg) 8 floats: total RB*L*SPLIT*8 = 256*8 floats = 8KB.
    __shared__ float partf[256][8];
#pragma unroll
    for (int t = 0; t < 8; t++) partf[tid][t] = ((a0[t] + a1[t]) + (a2[t] + a3[t]));
    __syncthreads();
    if (seg == 0 && valid) {
        float r[8];
#pragma unroll
        for (int t = 0; t < 8; t++) r[t] = partf[tid][t];
#pragma unroll
        for (int s2 = 1; s2 < SPLIT; s2++) {
#pragma unroll
            for (int t = 0; t < 8; t++) r[t] += partf[tid + s2 * L][t];
        }
        float inv = (len > 0) ? 1.f / (float)len : 0.f;
        uint4 o;
        o.x = pack2(r[0] * inv, r[1] * inv);
        o.y = pack2(r[2] * inv, r[3] * inv);
        o.z = pack2(r[4] * inv, r[5] * inv);
        o.w = pack2(r[6] * inv, r[7] * inv);
        dst[row * L + c] = o;
    }
}

// ---------------- bf16-source pull-gather (node side), vec-adj, prefetch-8 ----------------
template <int F, int S, bool BIAS_RELU, bool DST_BF16>
__global__ void gatherb(const uint4* __restrict__ src, const int* __restrict__ cur,
                        const u16* __restrict__ adj, const float4* __restrict__ bias,
                        void* __restrict__ dst, int nrows) {
    constexpr int L = F / 8;
    int gid = blockIdx.x * 256 + threadIdx.x;
    int row = gid / L;
    if (row >= nrows) return;
    int c = gid - row * L;
    int len = cur[row];
    int lenc = (len < S) ? len : S;
    int s = row * S, e = s + lenc;
    float a0[8] = {0,0,0,0,0,0,0,0}, a1[8] = {0,0,0,0,0,0,0,0};
    float a2[8] = {0,0,0,0,0,0,0,0}, a3[8] = {0,0,0,0,0,0,0,0};
    int j = s;
    for (; j + 7 < e; j += 8) {
        uint4 aa = *(const uint4*)(adj + j);
        int i0 = aa.x & 0xffff, i1 = aa.x >> 16;
        int i2 = aa.y & 0xffff, i3 = aa.y >> 16;
        int i4 = aa.z & 0xffff, i5 = aa.z >> 16;
        int i6 = aa.w & 0xffff, i7 = aa.w >> 16;
        uint4 v0 = src[i0 * L + c];
        uint4 v1 = src[i1 * L + c];
        uint4 v2 = src[i2 * L + c];
        uint4 v3 = src[i3 * L + c];
        uint4 v4 = src[i4 * L + c];
        uint4 v5 = src[i5 * L + c];
        uint4 v6 = src[i6 * L + c];
        uint4 v7 = src[i7 * L + c];
        acc8(a0, v0); acc8(a1, v1); acc8(a2, v2); acc8(a3, v3);
        acc8(a0, v4); acc8(a1, v5); acc8(a2, v6); acc8(a3, v7);
    }
    for (; j < e; j++) {
        uint4 v = src[(int)adj[j] * L + c];
        acc8(a0, v);
    }
    float inv = (len > 0) ? 1.f / (float)len : 0.f;
    float r[8];
#pragma unroll
    for (int t = 0; t < 8; t++) r[t] = ((a0[t] + a1[t]) + (a2[t] + a3[t])) * inv;
    if (BIAS_RELU) {
        float4 b0 = bias[c * 2], b1v = bias[c * 2 + 1];
        r[0] = fmaxf(r[0] + b0.x, 0.f); r[1] = fmaxf(r[1] + b0.y, 0.f);
        r[2] = fmaxf(r[2] + b0.z, 0.f); r[3] = fmaxf(r[3] + b0.w, 0.f);
        r[4] = fmaxf(r[4] + b1v.x, 0.f); r[5] = fmaxf(r[5] + b1v.y, 0.f);
        r[6] = fmaxf(r[6] + b1v.z, 0.f); r[7] = fmaxf(r[7] + b1v.w, 0.f);
    }
    if (DST_BF16) {
        uint4 o;
        o.x = pack2(r[0], r[1]);
        o.y = pack2(r[2], r[3]);
        o.z = pack2(r[4], r[5]);
        o.w = pack2(r[6], r[7]);
        ((uint4*)dst)[row * L + c] = o;
    } else {
        float4* d = (float4*)dst;
        d[row * (F / 4) + c * 2]     = make_float4(r[0], r[1], r[2], r[3]);
        d[row * (F / 4) + c * 2 + 1] = make_float4(r[4], r[5], r[6], r[7]);
    }
}

// ---------------- fused: sb = Dinv*gather_n(aggxb); hw = relu(sb@W1+b1)@W2 ----------------
#define SB_STRIDE 136
#define HSTRIDE 264
__global__ void gather_mlp(const uint4* __restrict__ aggxb4, const int* __restrict__ cur_n,
                           const u16* __restrict__ adj_n,
                           const short8* __restrict__ w1hi, const short8* __restrict__ w1lo,
                           const float* __restrict__ b1,
                           const short8* __restrict__ w2hi, const short8* __restrict__ w2lo,
                           u16* __restrict__ hw) {
    __shared__ u16 sbs[16 * SB_STRIDE];  // 4352 B
    __shared__ u16 hs[16 * HSTRIDE];     // 8448 B
    int tid = threadIdx.x;
    int node0 = blockIdx.x * 16;
    {
        int nl = tid >> 4;      // node local 0..15
        int c = tid & 15;       // uint4 column 0..15
        int node = node0 + nl;
        int len = cur_n[node];
        int lenc = (len < SN) ? len : SN;
        const u16* adj = adj_n + node * SN;
        float a0[8] = {0,0,0,0,0,0,0,0}, a1[8] = {0,0,0,0,0,0,0,0};
        float a2[8] = {0,0,0,0,0,0,0,0}, a3[8] = {0,0,0,0,0,0,0,0};
        int j = 0;
        for (; j + 7 < lenc; j += 8) {
            uint4 aa = *(const uint4*)(adj + j);
            int i0 = aa.x & 0xffff, i1 = aa.x >> 16;
            int i2 = aa.y & 0xffff, i3 = aa.y >> 16;
            int i4 = aa.z & 0xffff, i5 = aa.z >> 16;
            int i6 = aa.w & 0xffff, i7 = aa.w >> 16;
            uint4 v0 = aggxb4[i0 * 16 + c];
            uint4 v1 = aggxb4[i1 * 16 + c];
            uint4 v2 = aggxb4[i2 * 16 + c];
            uint4 v3 = aggxb4[i3 * 16 + c];
            uint4 v4 = aggxb4[i4 * 16 + c];
            uint4 v5 = aggxb4[i5 * 16 + c];
            uint4 v6 = aggxb4[i6 * 16 + c];
            uint4 v7 = aggxb4[i7 * 16 + c];
            acc8(a0, v0); acc8(a1, v1); acc8(a2, v2); acc8(a3, v3);
            acc8(a0, v4); acc8(a1, v5); acc8(a2, v6); acc8(a3, v7);
        }
        for (; j < lenc; j++) {
            uint4 v = aggxb4[(int)adj[j] * 16 + c];
            acc8(a0, v);
        }
        float inv = (len > 0) ? 1.f / (float)len : 0.f;
        float r[8];
#pragma unroll
        for (int t = 0; t < 8; t++) r[t] = ((a0[t] + a1[t]) + (a2[t] + a3[t])) * inv;
        u32* dstl = (u32*)&sbs[nl * SB_STRIDE + c * 8];
        dstl[0] = pack2(r[0], r[1]);
        dstl[1] = pack2(r[2], r[3]);
        dstl[2] = pack2(r[4], r[5]);
        dstl[3] = pack2(r[6], r[7]);
    }
    __syncthreads();
    int wave = tid >> 6;
    int lane = tid & 63;
    int m = lane & 15;
    int q = lane >> 4;
    short8 a[4];
#pragma unroll
    for (int kc = 0; kc < 4; kc++)
        a[kc] = *(const short8*)&sbs[m * SB_STRIDE + kc * 32 + q * 8];
#pragma unroll
    for (int i = 0; i < 4; i++) {
        int ct = wave * 4 + i;
        f32x4 acc = {0.f, 0.f, 0.f, 0.f};
#pragma unroll
        for (int kc = 0; kc < 4; kc++) {
            acc = __builtin_amdgcn_mfma_f32_16x16x32_bf16(a[kc], w1hi[(kc * 16 + ct) * 64 + lane], acc, 0, 0, 0);
            acc = __builtin_amdgcn_mfma_f32_16x16x32_bf16(a[kc], w1lo[(kc * 16 + ct) * 64 + lane], acc, 0, 0, 0);
        }
        int col = ct * 16 + m;   // C layout: col = lane&15, row = q*4+r
        float bc = b1[col];
#pragma unroll
        for (int r = 0; r < 4; r++) {
            float h = fmaxf(acc[r] + bc, 0.f);
            hs[(q * 4 + r) * HSTRIDE + col] = (u16)rne16(h);
        }
    }
    __syncthreads();
    f32x4 acc = {0.f, 0.f, 0.f, 0.f};
#pragma unroll
    for (int kc = 0; kc < 8; kc++) {
        short8 ah = *(const short8*)&hs[m * HSTRIDE + kc * 32 + q * 8];
        acc = __builtin_amdgcn_mfma_f32_16x16x32_bf16(ah, w2hi[(kc * 4 + wave) * 64 + lane], acc, 0, 0, 0);
        acc = __builtin_amdgcn_mfma_f32_16x16x32_bf16(ah, w2lo[(kc * 4 + wave) * 64 + lane], acc, 0, 0, 0);
    }
#pragma unroll
    for (int r = 0; r < 4; r++) {
        hw[(node0 + q * 4 + r) * D2 + wave * 16 + m] = (u16)rne16(acc[r]);
    }
}

extern "C" void kernel_launch(void* const* d_in, const int* in_sizes, int n_in,
                              void* d_out, int out_size, void* d_ws, size_t ws_size,
                              hipStream_t stream) {
    const float* x  = (const float*)d_in[0];
    const int* edge = (const int*)d_in[1];
    const int* nidx = edge;         // edge[0, :]
    const int* hidx = edge + NNZ;   // edge[1, :]
    const float* W1 = (const float*)d_in[2];
    const float* b1 = (const float*)d_in[3];
    const float* W2 = (const float*)d_in[4];
    const float* b2 = (const float*)d_in[5];
    float* out = (float*)d_out;

    // ---- workspace layout (all chunks 16B-aligned) ----
    u16* xb     = (u16*)d_ws;                 // 50000*128 u16 = 6,400,000
    u16* aggxb  = xb + N_NODES * IN_C;        // 5000*128  u16 = 640,000
    u16* hwb    = aggxb + N_HEDGES * IN_C;    // 50000*64  u16 = 3,200,000
    u16* e2b    = hwb + N_NODES * D2;         // 5000*64   u16 = 320,000
    u16* w1hi   = e2b + N_HEDGES * D2;        // 32768 u16
    u16* w1lo   = w1hi + 32768;               // 32768 u16
    u16* w2hi   = w1lo + 32768;               // 16384 u16
    u16* w2lo   = w2hi + 16384;               // 16384 u16
    u16* adj_n  = w2lo + 16384;               // 50000*64 u16 = 3,200,000
    u16* adj_h  = adj_n + N_NODES * SN;       // 5000*256 u16 = 1,280,000
    u32* pairs_h = (u32*)(adj_h + N_HEDGES * SH); // 250*4096 u32 = 4 MB
    u32* pairs_n = pairs_h + NHB * HCAP;          // 500*2048 u32 = 4 MB
    int* cur_n  = (int*)(pairs_n + NNB * NCAP);   // 50000 (written by build)
    int* cur_h  = cur_n + N_NODES;                // 5000  (written by build)
    int* gcur_h = cur_h + N_HEDGES;               // 256 (zeroed)
    int* gcur_n = gcur_h + 256;                   // 512 (zeroed)
    // total ≈ 17 MB

    hipMemsetAsync(gcur_h, 0, (256 + 512) * sizeof(int), stream);

    // fused: cast + W-pack + bucket
    cast_bucket<<<N_NODES * IN_C / 4 / 256, 256, 0, stream>>>(
        (const float4*)x, (uint2*)xb, W1, w1hi, w1lo, W2, w2hi, w2lo,
        nidx, hidx, gcur_h, gcur_n, pairs_h, pairs_n);

    build_adj<<<NHB + NNB, 256, 0, stream>>>(pairs_h, gcur_h, adj_h, cur_h,
                                             pairs_n, gcur_n, adj_n, cur_n);

    // aggxb = Binv * gather_h(xb)   [5000 x 128 bf16]  — split-K x4 (64 thr/row)
    gather_split<IN_C, SH, 4><<<(N_HEDGES + 3) / 4, 256, 0, stream>>>(
        (const uint4*)xb, cur_h, adj_h, (uint4*)aggxb, N_HEDGES);

    // fused: sb = Dinv*gather_n(aggxb); hw = relu(sb@W1+b1)@W2   [50000 x 64 bf16]
    gather_mlp<<<N_NODES / 16, 256, 0, stream>>>(
        (const uint4*)aggxb, cur_n, adj_n,
        (const short8*)w1hi, (const short8*)w1lo, b1,
        (const short8*)w2hi, (const short8*)w2lo, hwb);

    // layer 2: e2b = Binv * gather_h(hwb)  — split-K x8 (64 thr/row)
    gather_split<D2, SH, 8><<<(N_HEDGES + 3) / 4, 256, 0, stream>>>(
        (const uint4*)hwb, cur_h, adj_h, (uint4*)e2b, N_HEDGES);
    // out = relu(Dinv * gather_n(e2b) + b2)   [50000 x 64 f32]
    gatherb<D2, SN, true, false><<<(N_NODES * (D2 / 8) + 255) / 256, 256, 0, stream>>>(
        (const uint4*)e2b, cur_n, adj_n, (const float4*)b2, out, N_NODES);
}